// Round 3
// baseline (993.711 us; speedup 1.0000x reference)
//
#include <hip/hip_runtime.h>
#include <math.h>

#define BATCH 256
typedef unsigned int uint;
typedef unsigned short ushort;
typedef _Float16 half8 __attribute__((ext_vector_type(8)));
typedef float f32x4 __attribute__((ext_vector_type(4)));
typedef uint u32x4 __attribute__((ext_vector_type(4)));

#define GLOBAL_AS __attribute__((address_space(1)))
#define LDS_AS __attribute__((address_space(3)))

__device__ __forceinline__ ushort f2h(float f) {
  _Float16 h = (_Float16)f;
  return __builtin_bit_cast(ushort, h);
}
__device__ __forceinline__ float h2f(ushort u) {
  return (float)__builtin_bit_cast(_Float16, u);
}

// x fp32 [256][P=18^4] -> xt f16 [s=(t,d,h)][b=256][w=20]; cols 18,19 zeroed.
// w-innermost layout so conv can ds_read_b128 per-lane A fragments.
__global__ __launch_bounds__(256) void transpose_kernel(
    const float* __restrict__ x, ushort* __restrict__ xt) {
  const int td = blockIdx.x;        // t*18+d, 0..323
  const int bc = blockIdx.y * 64;   // batch chunk base
  const int tid = threadIdx.x;
  const int P = 104976;
  const int hh = (2 * tid) / 18, ww = (2 * tid) % 18;  // w-pair per thread
  const bool act = tid < 162;       // 162 pairs = 324 elems per (b, td-slab)
  for (int bb = 0; bb < 64; bb++) {
    const int b = bc + bb;
    if (act) {
      const float2 v =
          *(const float2*)(x + (size_t)b * P + td * 324 + 2 * tid);
      uint pk = (uint)f2h(v.x) | ((uint)f2h(v.y) << 16);
      *(uint*)(xt + ((size_t)(td * 18 + hh) * 256 + b) * 20 + ww) = pk;
    }
  }
  // zero pad cols 18,19 (read by wb=12 tiles with zero weights; must be finite)
  for (int e = tid; e < 18 * 64; e += 256) {
    const int h2 = e >> 6, b = bc + (e & 63);
    *(uint*)(xt + ((size_t)(td * 18 + h2) * 256 + b) * 20 + 18) = 0u;
  }
}

// Block-Toeplitz table: Bg[chunk][n=16][k=32] f16, chunk=(ci*KK+kt)*KK+kd,
// k=kh*8+wi, n=co*S+dw (co-major so C rows give w-contiguous stores).
// B[k][n] = w[co][ci][kt][kd][kh][wi-dw] when valid else 0.
template <int CIN, int COUT, int KK, int S>
__global__ __launch_bounds__(256) void build_b(
    const float* __restrict__ w, ushort* __restrict__ Bg) {
  const int chunk = blockIdx.x;
  const int kd = chunk % KK, kt = (chunk / KK) % KK, ci = chunk / (KK * KK);
  for (int e = threadIdx.x; e < 512; e += 256) {
    int n = e >> 5, k = e & 31;
    int kh = k >> 3, wi = k & 7;
    int co = n / S, dw = n % S;
    int kw = wi - dw;
    float v = 0.f;
    if (co < COUT && kh < KK && kw >= 0 && kw < KK)
      v = w[((((co * CIN + ci) * KK + kt) * KK + kd) * KK + kh) * KK + kw];
    Bg[chunk * 512 + n * 32 + k] = f2h(v);
  }
}

// MFMA implicit conv. Input layout [ci][t][d][h][b][WPIN] (w innermost,
// padded even). LDS row = [b=256][wi=8] (4KB) staged via global_load_lds
// (linear dest, per-lane w-window source; wb even => 4B-aligned src).
// A-operand = Toeplitz table (rows n), B-operand = x frag: ONE ds_read_b128
// per MFMA (lane stride 16B => structurally conflict-free), replacing 8x
// 8-way-conflicted ds_read_u16. C rows m=quad*4+reg = n=co*S+dw => each lane
// stores 4 (S=4) or 2+2 (S=2) consecutive w for its batch: contiguous stores.
template <int CIN, int COUT, int KK, int TI, int WPIN, int WPOUT, int S,
          int HB, bool ZTAIL>
__global__ __launch_bounds__(256) void conv_mfma(
    const ushort* __restrict__ xin, const ushort* __restrict__ Bg,
    const float* __restrict__ bias, ushort* __restrict__ out) {
  constexpr int WO = TI - KK + 1;
  constexpr int HTILES = WO / HB;  // exact in all configs
  constexpr int NC = CIN * KK * KK;
  constexpr int RS = 4 + HB - 1;   // staged h-rows (KHP=4)
  constexpr int ROWU = 8 * BATCH;  // 2048 u16 = [b=256][wi=8] row
  constexpr int sH = BATCH * WPIN, sD = TI * sH, sT = TI * sD, sC = TI * sT;
  constexpr int oH = BATCH * WPOUT, oD = WO * oH, oT = WO * oD, oC = WO * oT;

  __shared__ ushort slab[2][RS * ROWU];

  const int ht = blockIdx.x % HTILES;
  const int wt = blockIdx.x / HTILES;
  const int d = blockIdx.y, t = blockIdx.z;
  const int h0 = ht * HB, wb = wt * S;  // S even => wb even

  const int tid = threadIdx.x;
  const int wave = tid >> 6, lane = tid & 63;
  const int quad = lane >> 4, mm = lane & 15;

  f32x4 acc[HB][4];
#pragma unroll
  for (int dh = 0; dh < HB; dh++)
#pragma unroll
    for (int bt = 0; bt < 4; bt++) acc[dh][bt] = (f32x4){0.f, 0.f, 0.f, 0.f};

  auto stage = [&](int c, int buf) {
    const int kd = c % KK, kt2 = (c / KK) % KK, ci = c / (KK * KK);
    const ushort* base = xin + ci * sC + (t + kt2) * sT + (d + kd) * sD + wb;
    for (int r = wave; r < RS; r += 4) {
      int row = h0 + r;
      if (row > TI - 1) row = TI - 1;  // KK=3 tail rows (zero-weight) clamp
      const ushort* g = base + row * sH;
      ushort* l = &slab[buf][r * ROWU];
#pragma unroll
      for (int p = 0; p < 4; p++) {
        // lane writes l + p*1024B + lane*16B = batch (p*64+lane)'s 8-w window
        __builtin_amdgcn_global_load_lds(
            (const GLOBAL_AS uint*)(const void*)(g + (p * 64 + lane) * WPIN),
            (LDS_AS uint*)(void*)(l + p * 512), 16, 0, 0);
      }
    }
  };

  stage(0, 0);

  for (int c = 0; c < NC; c++) {
    __syncthreads();  // slab[c&1] ready; everyone done with slab[(c+1)&1]
    if (c + 1 < NC) stage(c + 1, (c + 1) & 1);

    u32x4 traw = *(const u32x4*)(const void*)(Bg + c * 512 + mm * 32 + quad * 8);
    half8 tf = __builtin_bit_cast(half8, traw);
    const int buf = c & 1;

#pragma unroll
    for (int dh = 0; dh < HB; dh++) {
      const ushort* arow = &slab[buf][(dh + quad) * ROWU];
#pragma unroll
      for (int bt = 0; bt < 4; bt++) {
        const int b0 = (wave * 4 + bt) * 16;
        half8 xf = __builtin_bit_cast(
            half8, *(const u32x4*)(const void*)(arow + (b0 + mm) * 8));
        acc[dh][bt] =
            __builtin_amdgcn_mfma_f32_16x16x32_f16(tf, xf, acc[dh][bt], 0, 0, 0);
      }
    }
  }

  // Epilogue: C/D row m=quad*4+reg = n (co*S+dw); col = mm = batch-in-16.
#pragma unroll
  for (int dh = 0; dh < HB; dh++)
#pragma unroll
    for (int bt = 0; bt < 4; bt++) {
      const int b = (wave * 4 + bt) * 16 + mm;
      ushort* orow = out + t * oT + d * oD + (h0 + dh) * oH + b * WPOUT + wb;
      f32x4 v = acc[dh][bt];
      if constexpr (S == 4) {
        const int co = quad;
        if (co < COUT) {
          const float bv = bias[co];
          float r0 = fmaxf(v[0] + bv, 0.f), r1 = fmaxf(v[1] + bv, 0.f);
          float r2 = fmaxf(v[2] + bv, 0.f), r3 = fmaxf(v[3] + bv, 0.f);
          uint2 pk;
          pk.x = (uint)f2h(r0) | ((uint)f2h(r1) << 16);
          pk.y = (uint)f2h(r2) | ((uint)f2h(r3) << 16);
          *(uint2*)(void*)(orow + co * oC) = pk;  // 4 consecutive w, 8B aligned
        }
      } else {  // S == 2: regs (0,1)->co0, (2,3)->co1
        const int co0 = quad * 2, co1 = co0 + 1;
        if (co0 < COUT) {
          const float bv = bias[co0];
          float r0 = fmaxf(v[0] + bv, 0.f), r1 = fmaxf(v[1] + bv, 0.f);
          *(uint*)(void*)(orow + co0 * oC) =
              (uint)f2h(r0) | ((uint)f2h(r1) << 16);
        }
        if (co1 < COUT) {
          const float bv = bias[co1];
          float r2 = fmaxf(v[2] + bv, 0.f), r3 = fmaxf(v[3] + bv, 0.f);
          *(uint*)(void*)(orow + co1 * oC) =
              (uint)f2h(r2) | ((uint)f2h(r3) << 16);
        }
      }
      if constexpr (ZTAIL) {
        // Last w-tile zero-fills pad cols [WO,WPOUT) so next layer's staged
        // windows read finite values (garbage*0-weight is fine, NaN is not).
        if (wb + S == WO) {
          ushort* zrow = out + t * oT + d * oD + (h0 + dh) * oH + b * WPOUT;
          if constexpr (S == 4) {
            if (quad < COUT) {
#pragma unroll
              for (int j = 0; j < (WPOUT - WO) / 2; j++)
                *(uint*)(void*)(zrow + quad * oC + WO + 2 * j) = 0u;
            }
          } else {
            const int cz = quad * 2;
#pragma unroll
            for (int cc = 0; cc < 2; cc++)
              if (cz + cc < COUT) {
#pragma unroll
                for (int j = 0; j < (WPOUT - WO) / 2; j++)
                  *(uint*)(void*)(zrow + (cz + cc) * oC + WO + 2 * j) = 0u;
              }
          }
        }
      }
    }
}

// h5 f16 [co][t][d][h][b][4] => k-quad major: u64-coalesced per batch.
__global__ __launch_bounds__(256) void fc1_kernel(
    const ushort* __restrict__ h, const float* __restrict__ w,
    const float* __restrict__ bias, float* __restrict__ out) {
  const int o = blockIdx.x, b = threadIdx.x;
  const float* wr = w + o * 1280;
  float a0 = 0.f, a1 = 0.f, a2 = 0.f, a3 = 0.f;
#pragma unroll 4
  for (int kq = 0; kq < 320; kq++) {
    const uint2 hv = *(const uint2*)(const void*)(h + (kq * 256 + b) * 4);
    a0 = fmaf(h2f((ushort)(hv.x & 0xffffu)), wr[4 * kq + 0], a0);
    a1 = fmaf(h2f((ushort)(hv.x >> 16)), wr[4 * kq + 1], a1);
    a2 = fmaf(h2f((ushort)(hv.y & 0xffffu)), wr[4 * kq + 2], a2);
    a3 = fmaf(h2f((ushort)(hv.y >> 16)), wr[4 * kq + 3], a3);
  }
  float acc = (a0 + a1) + (a2 + a3) + bias[o];
  out[o * BATCH + b] = acc > 0.f ? acc : 0.f;
}

__global__ __launch_bounds__(256) void fc2_kernel(
    const float* __restrict__ r, const float* __restrict__ w,
    const float* __restrict__ bias, float* __restrict__ out) {
  const int b = threadIdx.x;
  float acc = bias[0];
#pragma unroll
  for (int o = 0; o < 33; o++) acc = fmaf(r[o * BATCH + b], w[o], acc);
  out[b] = 1.f / (1.f + expf(-acc));
}

extern "C" void kernel_launch(void* const* d_in, const int* in_sizes, int n_in,
                              void* d_out, int out_size, void* d_ws,
                              size_t ws_size, hipStream_t stream) {
  const float* x    = (const float*)d_in[0];
  const float* w1   = (const float*)d_in[1];
  const float* b1   = (const float*)d_in[2];
  const float* w2   = (const float*)d_in[3];
  const float* b2   = (const float*)d_in[4];
  const float* w3   = (const float*)d_in[5];
  const float* b3   = (const float*)d_in[6];
  const float* w4   = (const float*)d_in[7];
  const float* b4   = (const float*)d_in[8];
  const float* w5   = (const float*)d_in[9];
  const float* b5   = (const float*)d_in[10];
  const float* fc1w = (const float*)d_in[11];
  const float* fc1b = (const float*)d_in[12];
  const float* fc2w = (const float*)d_in[13];
  const float* fc2b = (const float*)d_in[14];
  float* out = (float*)d_out;

  // Workspace (u16 units). All layouts [c][t][d][h][b][WP] (w innermost, even
  // WP sized so every staged 8-wide w-window is in-row; no OOB reads).
  // R0: xt 29,859,840 / h2 21,233,664 / h4 2,764,800
  // R1: h1 41,472,000 / h3  8,957,952 / h5   327,680
  ushort* wsu = (ushort*)d_ws;
  ushort* R0 = wsu;
  ushort* R1 = wsu + 29900000;
  ushort* Bgb = wsu + 71400000;      // 221*512 = 113,152 u16
  float* fo = (float*)(wsu + 71520000);

  ushort* xt = R0;
  ushort* h1 = R1;
  ushort* h2 = R0;
  ushort* h3 = R1;
  ushort* h4 = R0;
  ushort* h5 = R1;

  ushort* B1 = Bgb;                 // 16 chunks
  ushort* B2 = Bgb + 16 * 512;      // 48
  ushort* B3 = Bgb + 64 * 512;      // 48
  ushort* B4 = Bgb + 112 * 512;     // 64
  ushort* B5 = Bgb + 176 * 512;     // 45

  build_b<1, 3, 4, 4><<<16, 256, 0, stream>>>(w1, B1);
  build_b<3, 3, 4, 4><<<48, 256, 0, stream>>>(w2, B2);
  build_b<3, 4, 4, 4><<<48, 256, 0, stream>>>(w3, B3);
  build_b<4, 5, 4, 2><<<64, 256, 0, stream>>>(w4, B4);
  build_b<5, 5, 3, 2><<<45, 256, 0, stream>>>(w5, B5);

  transpose_kernel<<<dim3(324, 4), 256, 0, stream>>>(x, xt);

  // <CIN,COUT,KK,TI,WPIN,WPOUT,S,HB,ZTAIL> grid(x = wt*HTILES+ht, y=d, z=t)
  conv_mfma<1, 3, 4, 18, 20, 16, 4, 3, false>
      <<<dim3(20, 15, 15), 256, 0, stream>>>(xt, B1, b1, h1);
  conv_mfma<3, 3, 4, 15, 16, 16, 4, 3, true>
      <<<dim3(12, 12, 12), 256, 0, stream>>>(h1, B2, b2, h2);
  conv_mfma<3, 4, 4, 12, 16, 12, 4, 3, false>
      <<<dim3(9, 9, 9), 256, 0, stream>>>(h2, B3, b3, h3);
  conv_mfma<4, 5, 4, 9, 12, 10, 2, 2, true>
      <<<dim3(9, 6, 6), 256, 0, stream>>>(h3, B4, b4, h4);
  conv_mfma<5, 5, 3, 6, 10, 4, 2, 2, false>
      <<<dim3(4, 4, 4), 256, 0, stream>>>(h4, B5, b5, h5);

  fc1_kernel<<<33, 256, 0, stream>>>(h5, fc1w, fc1b, fo);
  fc2_kernel<<<1, 256, 0, stream>>>(fo, fc2w, fc2b, out);
}

// Round 4
// 778.095 us; speedup vs baseline: 1.2771x; 1.2771x over previous
//
#include <hip/hip_runtime.h>
#include <math.h>

#define BATCH 256
typedef unsigned int uint;
typedef unsigned short ushort;
typedef _Float16 half8 __attribute__((ext_vector_type(8)));
typedef float f32x4 __attribute__((ext_vector_type(4)));
typedef uint u32x4 __attribute__((ext_vector_type(4)));

#define GLOBAL_AS __attribute__((address_space(1)))
#define LDS_AS __attribute__((address_space(3)))

__device__ __forceinline__ ushort f2h(float f) {
  _Float16 h = (_Float16)f;
  return __builtin_bit_cast(ushort, h);
}
__device__ __forceinline__ float h2f(ushort u) {
  return (float)__builtin_bit_cast(_Float16, u);
}

// x fp32 [256][P=18^4] -> xt f16 group layout [slab=(t,d,h)][g=5][b=256][4w].
// Aligned 4-w groups: an 8-wide window at wb%4==0 is two ADJACENT group-rows
// = 4KB contiguous (coalesced staging) AND per-lane w-contiguous (b64 reads).
// Pads w18,19 (group 4, off 2,3) zeroed.
__global__ __launch_bounds__(256) void transpose_kernel(
    const float* __restrict__ x, ushort* __restrict__ xt) {
  const int td = blockIdx.x;        // t*18+d, 0..323
  const int bc = blockIdx.y * 64;   // batch chunk base
  const int tid = threadIdx.x;
  const int P = 104976;
  const int hh = (2 * tid) / 18, ww = (2 * tid) % 18;  // w-pair per thread
  const bool act = tid < 162;       // 162 pairs = 324 elems per (b, td-slab)
  for (int bb = 0; bb < 64; bb++) {
    const int b = bc + bb;
    if (act) {
      const float2 v =
          *(const float2*)(x + (size_t)b * P + td * 324 + 2 * tid);
      uint pk = (uint)f2h(v.x) | ((uint)f2h(v.y) << 16);
      *(uint*)(xt + (((size_t)(td * 18 + hh) * 5 + (ww >> 2)) * 256 + b) * 4 +
               (ww & 3)) = pk;
    }
  }
  // zero pads w18,19 = group 4 offsets 2,3
  for (int e = tid; e < 18 * 64; e += 256) {
    const int h2 = e >> 6, b = bc + (e & 63);
    *(uint*)(xt + (((size_t)(td * 18 + h2) * 5 + 4) * 256 + b) * 4 + 2) = 0u;
  }
}

// Block-Toeplitz table: Bg[chunk][n=16][k=32] f16, chunk=(ci*KK+kt)*KK+kd,
// k=kh*8+wi, n=co*S+dw. B[k][n] = w[co][ci][kt][kd][kh][wi-dw] if valid else 0.
template <int CIN, int COUT, int KK, int S>
__global__ __launch_bounds__(256) void build_b(
    const float* __restrict__ w, ushort* __restrict__ Bg) {
  const int chunk = blockIdx.x;
  const int kd = chunk % KK, kt = (chunk / KK) % KK, ci = chunk / (KK * KK);
  for (int e = threadIdx.x; e < 512; e += 256) {
    int n = e >> 5, k = e & 31;
    int kh = k >> 3, wi = k & 7;
    int co = n / S, dw = n % S;
    int kw = wi - dw;
    float v = 0.f;
    if (co < COUT && kh < KK && kw >= 0 && kw < KK)
      v = w[((((co * CIN + ci) * KK + kt) * KK + kd) * KK + kh) * KK + kw];
    Bg[chunk * 512 + n * 32 + k] = f2h(v);
  }
}

// MFMA implicit conv on group layout [ci][t][d][h][g][b][4w].
// Staging: GW adjacent group-rows per h-row (GW*2KB contiguous) via
// global_load_lds, linear dest, coalesced 16B/lane source. Double-buffered.
// Fragment: 2x ds_read_b64 (slots 0,1; lane stride 8B = conflict-free);
// S=2 misaligned (wb&2): b32+b64+b32 across slots 0,1,2.
// C rows m=quad*4+reg = n=co*S+dw -> contiguous w per lane; aligned stores.
template <int CIN, int COUT, int KK, int TI, int GIN, int GOUT, int S, int HB,
          int PADSTART, int PADEND>
__global__ __launch_bounds__(256) void conv_mfma(
    const ushort* __restrict__ xin, const ushort* __restrict__ Bg,
    const float* __restrict__ bias, ushort* __restrict__ out) {
  constexpr int WO = TI - KK + 1;
  constexpr int HTILES = WO / HB;    // exact in all configs
  constexpr int NC = CIN * KK * KK;
  constexpr int RS = 4 + HB - 1;     // staged h-rows (KHP=4)
  constexpr int GW = (S == 4 ? 2 : 3);  // staged group-rows per h-row
  constexpr int ROWU = GW * 1024;    // u16 per staged h-row
  constexpr int PROW = GW * 2;       // 1KB chunks per row (64 lanes x 16B)
  constexpr int sH = GIN * 1024, sD = TI * sH, sT = TI * sD, sC = TI * sT;
  constexpr int oH = GOUT * 1024, oD = WO * oH, oT = WO * oD, oC = WO * oT;

  __shared__ ushort slab[2][RS * ROWU];

  const int ht = blockIdx.x % HTILES;
  const int wt = blockIdx.x / HTILES;
  const int d = blockIdx.y, t = blockIdx.z;
  const int h0 = ht * HB, wb = wt * S;
  const int g0 = wb >> 2;

  const int tid = threadIdx.x;
  const int wave = tid >> 6, lane = tid & 63;
  const int quad = lane >> 4, mm = lane & 15;

  f32x4 acc[HB][4];
#pragma unroll
  for (int dh = 0; dh < HB; dh++)
#pragma unroll
    for (int bt = 0; bt < 4; bt++) acc[dh][bt] = (f32x4){0.f, 0.f, 0.f, 0.f};

  auto stage = [&](int c, int buf) {
    const int kd = c % KK, kt2 = (c / KK) % KK, ci = c / (KK * KK);
    const ushort* base =
        xin + ci * sC + (t + kt2) * sT + (d + kd) * sD + g0 * 1024;
    for (int r = wave; r < RS; r += 4) {
      int row = h0 + r;
      if (row > TI - 1) row = TI - 1;  // KK=3 tail rows (zero-weight) clamp
      const ushort* g = base + row * sH;
      ushort* l = &slab[buf][r * ROWU];
#pragma unroll
      for (int p = 0; p < PROW; p++) {
        // lane writes l + p*1024B + lane*16B <- contiguous global 16B chunk
        __builtin_amdgcn_global_load_lds(
            (const GLOBAL_AS uint*)(const void*)(g + p * 512 + lane * 8),
            (LDS_AS uint*)(void*)(l + p * 512), 16, 0, 0);
      }
    }
  };

  stage(0, 0);

  for (int c = 0; c < NC; c++) {
    __syncthreads();  // slab[c&1] ready; everyone done with slab[(c+1)&1]
    if (c + 1 < NC) stage(c + 1, (c + 1) & 1);

    u32x4 traw = *(const u32x4*)(const void*)(Bg + c * 512 + mm * 32 + quad * 8);
    half8 tf = __builtin_bit_cast(half8, traw);
    const int buf = c & 1;

#pragma unroll
    for (int dh = 0; dh < HB; dh++) {
      const ushort* arow = &slab[buf][(dh + quad) * ROWU];
#pragma unroll
      for (int bt = 0; bt < 4; bt++) {
        const int bidx = ((wave * 4 + bt) * 16 + mm) * 4;
        u32x4 raw;
        if constexpr (S == 4) {
          uint2 lo = *(const uint2*)(const void*)(arow + bidx);
          uint2 hi = *(const uint2*)(const void*)(arow + 1024 + bidx);
          raw = (u32x4){lo.x, lo.y, hi.x, hi.y};
        } else {
          if ((wb & 2) == 0) {
            uint2 lo = *(const uint2*)(const void*)(arow + bidx);
            uint2 hi = *(const uint2*)(const void*)(arow + 1024 + bidx);
            raw = (u32x4){lo.x, lo.y, hi.x, hi.y};
          } else {
            uint c0 = *(const uint*)(const void*)(arow + bidx + 2);
            uint2 md = *(const uint2*)(const void*)(arow + 1024 + bidx);
            uint c1 = *(const uint*)(const void*)(arow + 2048 + bidx);
            raw = (u32x4){c0, md.x, md.y, c1};
          }
        }
        half8 xf = __builtin_bit_cast(half8, raw);
        acc[dh][bt] =
            __builtin_amdgcn_mfma_f32_16x16x32_f16(tf, xf, acc[dh][bt], 0, 0, 0);
      }
    }
  }

  // Epilogue: C/D row m=quad*4+reg = n (co*S+dw); col = mm = batch-in-16.
  const bool is_last = (wb + S >= WO);
#pragma unroll
  for (int dh = 0; dh < HB; dh++)
#pragma unroll
    for (int bt = 0; bt < 4; bt++) {
      const int b = (wave * 4 + bt) * 16 + mm;
      ushort* obase = out + t * oT + d * oD + (h0 + dh) * oH + b * 4;
      f32x4 v = acc[dh][bt];
      if constexpr (S == 4) {
        const int co = quad;
        if (co < COUT) {
          const float bv = bias[co];
          // in-pair force-zero for w >= WO (covers h1 w15, h3 w9..11)
          float r0 = (wb + 0 < WO) ? fmaxf(v[0] + bv, 0.f) : 0.f;
          float r1 = (wb + 1 < WO) ? fmaxf(v[1] + bv, 0.f) : 0.f;
          float r2 = (wb + 2 < WO) ? fmaxf(v[2] + bv, 0.f) : 0.f;
          float r3 = (wb + 3 < WO) ? fmaxf(v[3] + bv, 0.f) : 0.f;
          uint2 pk;
          pk.x = (uint)f2h(r0) | ((uint)f2h(r1) << 16);
          pk.y = (uint)f2h(r2) | ((uint)f2h(r3) << 16);
          *(uint2*)(void*)(obase + co * oC + g0 * 1024) = pk;
          if constexpr (PADEND > PADSTART) {
            if (is_last) {
#pragma unroll
              for (int w = PADSTART; w < PADEND; w += 2)
                *(uint*)(void*)(obase + co * oC + (w >> 2) * 1024 + (w & 3)) =
                    0u;
            }
          }
        }
      } else {  // S == 2: regs (0,1)->co0, (2,3)->co1
        const int co0 = quad * 2, co1 = co0 + 1;
        if (co0 < COUT) {
          const float bv = bias[co0];
          float r0 = fmaxf(v[0] + bv, 0.f), r1 = fmaxf(v[1] + bv, 0.f);
          *(uint*)(void*)(obase + co0 * oC + g0 * 1024 + (wb & 3)) =
              (uint)f2h(r0) | ((uint)f2h(r1) << 16);
        }
        if (co1 < COUT) {
          const float bv = bias[co1];
          float r2 = fmaxf(v[2] + bv, 0.f), r3 = fmaxf(v[3] + bv, 0.f);
          *(uint*)(void*)(obase + co1 * oC + g0 * 1024 + (wb & 3)) =
              (uint)f2h(r2) | ((uint)f2h(r3) << 16);
        }
        if constexpr (PADEND > PADSTART) {
          if (is_last) {
#pragma unroll
            for (int cc = 0; cc < 2; cc++) {
              const int co = quad * 2 + cc;
              if (co < COUT) {
#pragma unroll
                for (int w = PADSTART; w < PADEND; w += 2)
                  *(uint*)(void*)(obase + co * oC + (w >> 2) * 1024 +
                                  (w & 3)) = 0u;
              }
            }
          }
        }
      }
    }
}

// h5 f16 [co][t][d][h][b][4] (= group layout, GOUT=1): u64-coalesced.
__global__ __launch_bounds__(256) void fc1_kernel(
    const ushort* __restrict__ h, const float* __restrict__ w,
    const float* __restrict__ bias, float* __restrict__ out) {
  const int o = blockIdx.x, b = threadIdx.x;
  const float* wr = w + o * 1280;
  float a0 = 0.f, a1 = 0.f, a2 = 0.f, a3 = 0.f;
#pragma unroll 4
  for (int kq = 0; kq < 320; kq++) {
    const uint2 hv = *(const uint2*)(const void*)(h + (kq * 256 + b) * 4);
    a0 = fmaf(h2f((ushort)(hv.x & 0xffffu)), wr[4 * kq + 0], a0);
    a1 = fmaf(h2f((ushort)(hv.x >> 16)), wr[4 * kq + 1], a1);
    a2 = fmaf(h2f((ushort)(hv.y & 0xffffu)), wr[4 * kq + 2], a2);
    a3 = fmaf(h2f((ushort)(hv.y >> 16)), wr[4 * kq + 3], a3);
  }
  float acc = (a0 + a1) + (a2 + a3) + bias[o];
  out[o * BATCH + b] = acc > 0.f ? acc : 0.f;
}

__global__ __launch_bounds__(256) void fc2_kernel(
    const float* __restrict__ r, const float* __restrict__ w,
    const float* __restrict__ bias, float* __restrict__ out) {
  const int b = threadIdx.x;
  float acc = bias[0];
#pragma unroll
  for (int o = 0; o < 33; o++) acc = fmaf(r[o * BATCH + b], w[o], acc);
  out[b] = 1.f / (1.f + expf(-acc));
}

extern "C" void kernel_launch(void* const* d_in, const int* in_sizes, int n_in,
                              void* d_out, int out_size, void* d_ws,
                              size_t ws_size, hipStream_t stream) {
  const float* x    = (const float*)d_in[0];
  const float* w1   = (const float*)d_in[1];
  const float* b1   = (const float*)d_in[2];
  const float* w2   = (const float*)d_in[3];
  const float* b2   = (const float*)d_in[4];
  const float* w3   = (const float*)d_in[5];
  const float* b3   = (const float*)d_in[6];
  const float* w4   = (const float*)d_in[7];
  const float* b4   = (const float*)d_in[8];
  const float* w5   = (const float*)d_in[9];
  const float* b5   = (const float*)d_in[10];
  const float* fc1w = (const float*)d_in[11];
  const float* fc1b = (const float*)d_in[12];
  const float* fc2w = (const float*)d_in[13];
  const float* fc2b = (const float*)d_in[14];
  float* out = (float*)d_out;

  // Workspace (u16 units), group layout [c][t][d][h][g][b][4]:
  // R0: xt 29,859,840 (G=5) / h2 21,233,664 (G=4) / h4 3,317,760 (G=3)
  // R1: h1 41,472,000 (G=4) / h3  8,957,952 (G=3) / h5   327,680 (G=1)
  // Staging may overread ~6KB past tensor ends (clamped rows / extra GW slot)
  // -> margins between regions; never frag-read, harmless if garbage.
  ushort* wsu = (ushort*)d_ws;
  ushort* R0 = wsu;
  ushort* R1 = wsu + 29900000;
  ushort* Bgb = wsu + 71400000;      // 221*512 = 113,152 u16
  float* fo = (float*)(wsu + 71520000);

  ushort* xt = R0;
  ushort* h1 = R1;
  ushort* h2 = R0;
  ushort* h3 = R1;
  ushort* h4 = R0;
  ushort* h5 = R1;

  ushort* B1 = Bgb;                 // 16 chunks
  ushort* B2 = Bgb + 16 * 512;      // 48
  ushort* B3 = Bgb + 64 * 512;      // 48
  ushort* B4 = Bgb + 112 * 512;     // 64
  ushort* B5 = Bgb + 176 * 512;     // 45

  build_b<1, 3, 4, 4><<<16, 256, 0, stream>>>(w1, B1);
  build_b<3, 3, 4, 4><<<48, 256, 0, stream>>>(w2, B2);
  build_b<3, 4, 4, 4><<<48, 256, 0, stream>>>(w3, B3);
  build_b<4, 5, 4, 2><<<64, 256, 0, stream>>>(w4, B4);
  build_b<5, 5, 3, 2><<<45, 256, 0, stream>>>(w5, B5);

  transpose_kernel<<<dim3(324, 4), 256, 0, stream>>>(x, xt);

  // <CIN,COUT,KK,TI,GIN,GOUT,S,HB,PADSTART,PADEND> grid(x=wt*HTILES+ht,y=d,z=t)
  conv_mfma<1, 3, 4, 18, 5, 4, 4, 3, 0, 0>
      <<<dim3(20, 15, 15), 256, 0, stream>>>(xt, B1, b1, h1);
  conv_mfma<3, 3, 4, 15, 4, 4, 4, 3, 12, 16>
      <<<dim3(12, 12, 12), 256, 0, stream>>>(h1, B2, b2, h2);
  conv_mfma<3, 4, 4, 12, 4, 3, 4, 3, 0, 0>
      <<<dim3(9, 9, 9), 256, 0, stream>>>(h2, B3, b3, h3);
  conv_mfma<4, 5, 4, 9, 3, 3, 2, 2, 6, 12>
      <<<dim3(9, 6, 6), 256, 0, stream>>>(h3, B4, b4, h4);
  conv_mfma<5, 5, 3, 6, 3, 1, 2, 2, 0, 0>
      <<<dim3(4, 4, 4), 256, 0, stream>>>(h4, B5, b5, h5);

  fc1_kernel<<<33, 256, 0, stream>>>(h5, fc1w, fc1b, fo);
  fc2_kernel<<<1, 256, 0, stream>>>(fo, fc2w, fc2b, out);
}

// Round 5
// 770.159 us; speedup vs baseline: 1.2903x; 1.0103x over previous
//
#include <hip/hip_runtime.h>
#include <math.h>

#define BATCH 256
typedef unsigned int uint;
typedef unsigned short ushort;
typedef _Float16 half8 __attribute__((ext_vector_type(8)));
typedef float f32x4 __attribute__((ext_vector_type(4)));
typedef uint u32x4 __attribute__((ext_vector_type(4)));

#define GLOBAL_AS __attribute__((address_space(1)))
#define LDS_AS __attribute__((address_space(3)))

__device__ __forceinline__ ushort f2h(float f) {
  _Float16 h = (_Float16)f;
  return __builtin_bit_cast(ushort, h);
}
__device__ __forceinline__ float h2f(ushort u) {
  return (float)__builtin_bit_cast(_Float16, u);
}

// x fp32 [256][P=18^4] -> xt group layout [sh=(t,d,h)][g=5][b=256][4w] u16.
// 64x64 u32-tile LDS transpose: coalesced 512B global reads AND uint2 writes.
// pp = w-pair index = sh*9 + wp (wp 0..8; w = 2*wp). Out u32 index:
// (sh*5+g)*512 + b*2 + slot, pairs (slot0,slot1) = (wp=2g, wp=2g+1);
// wp==8 pairs with zero -> pad w18,19 written for free.
__global__ __launch_bounds__(256) void transpose_kernel(
    const float* __restrict__ x, uint* __restrict__ xt) {
  __shared__ uint tile[65][65];
  const int P = 104976, NPP = 52488;
  const int pp0 = blockIdx.x * 64, b0 = blockIdx.y * 64;
  const int tx = threadIdx.x & 63, ty = threadIdx.x >> 6;
  // read: lane tx = pp-local (coalesced float2), ty+r = b-local
  for (int r = 0; r < 64; r += 4) {
    const int bl = ty + r, pp = pp0 + tx;
    if (pp < NPP) {
      const float2 v = *(const float2*)(x + (size_t)(b0 + bl) * P + 2 * pp);
      tile[tx][bl] = (uint)f2h(v.x) | ((uint)f2h(v.y) << 16);
    }
  }
  // extra pp row 64: pair partner for row 63
  if (threadIdx.x < 64 && pp0 + 64 < NPP) {
    const int bl = threadIdx.x;
    const float2 v =
        *(const float2*)(x + (size_t)(b0 + bl) * P + 2 * (pp0 + 64));
    tile[64][bl] = (uint)f2h(v.x) | ((uint)f2h(v.y) << 16);
  }
  __syncthreads();
  // write: wave ty handles rows r==ty (mod 4); lane tx = b-local
  for (int r = ty; r < 64; r += 4) {
    const int pp = pp0 + r;
    if (pp >= NPP) break;
    const int wp = pp % 9, sh = pp / 9;
    if (wp & 1) continue;  // odd wp covered as pair partner
    uint2 o;
    o.x = tile[r][tx];
    o.y = (wp == 8) ? 0u : tile[r + 1][tx];
    *(uint2*)(xt + (size_t)(sh * 5 + (wp >> 1)) * 512 + (b0 + tx) * 2) = o;
  }
}

// Block-Toeplitz table: Bg[chunk][n=16][k=32] f16, chunk=(ci*KK+kt)*KK+kd,
// k=kh*8+wi, n=co*S+dw. B[k][n] = w[co][ci][kt][kd][kh][wi-dw] if valid else 0.
template <int CIN, int COUT, int KK, int S>
__global__ __launch_bounds__(256) void build_b(
    const float* __restrict__ w, ushort* __restrict__ Bg) {
  const int chunk = blockIdx.x;
  const int kd = chunk % KK, kt = (chunk / KK) % KK, ci = chunk / (KK * KK);
  for (int e = threadIdx.x; e < 512; e += 256) {
    int n = e >> 5, k = e & 31;
    int kh = k >> 3, wi = k & 7;
    int co = n / S, dw = n % S;
    int kw = wi - dw;
    float v = 0.f;
    if (co < COUT && kh < KK && kw >= 0 && kw < KK)
      v = w[((((co * CIN + ci) * KK + kt) * KK + kd) * KK + kh) * KK + kw];
    Bg[chunk * 512 + n * 32 + k] = f2h(v);
  }
}

// MFMA implicit conv on group layout [ci][t][d][h][g][b][4w].
// Staging: GW adjacent group-rows per h-row (GW*2KB contiguous) via
// global_load_lds, linear dest, coalesced 16B/lane source. Double-buffered.
// Fragment: 2x ds_read_b64 (slots 0,1; lane stride 8B = conflict-free);
// S=2 misaligned (wb&2): b32+b64+b32 across slots 0,1,2.
// C rows m=quad*4+reg = n=co*S+dw -> contiguous w per lane; aligned stores.
template <int CIN, int COUT, int KK, int TI, int GIN, int GOUT, int S, int HB,
          int PADSTART, int PADEND>
__global__ __launch_bounds__(256) void conv_mfma(
    const ushort* __restrict__ xin, const ushort* __restrict__ Bg,
    const float* __restrict__ bias, ushort* __restrict__ out) {
  constexpr int WO = TI - KK + 1;
  constexpr int HTILES = WO / HB;    // exact in all configs
  constexpr int NC = CIN * KK * KK;
  constexpr int RS = 4 + HB - 1;     // staged h-rows (KHP=4)
  constexpr int GW = (S == 4 ? 2 : 3);  // staged group-rows per h-row
  constexpr int ROWU = GW * 1024;    // u16 per staged h-row
  constexpr int PROW = GW * 2;       // 1KB chunks per row (64 lanes x 16B)
  constexpr int sH = GIN * 1024, sD = TI * sH, sT = TI * sD, sC = TI * sT;
  constexpr int oH = GOUT * 1024, oD = WO * oH, oT = WO * oD, oC = WO * oT;

  __shared__ ushort slab[2][RS * ROWU];

  const int ht = blockIdx.x % HTILES;
  const int wt = blockIdx.x / HTILES;
  const int d = blockIdx.y, t = blockIdx.z;
  const int h0 = ht * HB, wb = wt * S;
  const int g0 = wb >> 2;

  const int tid = threadIdx.x;
  const int wave = tid >> 6, lane = tid & 63;
  const int quad = lane >> 4, mm = lane & 15;

  f32x4 acc[HB][4];
#pragma unroll
  for (int dh = 0; dh < HB; dh++)
#pragma unroll
    for (int bt = 0; bt < 4; bt++) acc[dh][bt] = (f32x4){0.f, 0.f, 0.f, 0.f};

  auto stage = [&](int c, int buf) {
    const int kd = c % KK, kt2 = (c / KK) % KK, ci = c / (KK * KK);
    const ushort* base =
        xin + ci * sC + (t + kt2) * sT + (d + kd) * sD + g0 * 1024;
    for (int r = wave; r < RS; r += 4) {
      int row = h0 + r;
      if (row > TI - 1) row = TI - 1;  // KK=3 tail rows (zero-weight) clamp
      const ushort* g = base + row * sH;
      ushort* l = &slab[buf][r * ROWU];
#pragma unroll
      for (int p = 0; p < PROW; p++) {
        // lane writes l + p*1024B + lane*16B <- contiguous global 16B chunk
        __builtin_amdgcn_global_load_lds(
            (const GLOBAL_AS uint*)(const void*)(g + p * 512 + lane * 8),
            (LDS_AS uint*)(void*)(l + p * 512), 16, 0, 0);
      }
    }
  };

  stage(0, 0);

  for (int c = 0; c < NC; c++) {
    __syncthreads();  // slab[c&1] ready; everyone done with slab[(c+1)&1]
    if (c + 1 < NC) stage(c + 1, (c + 1) & 1);

    u32x4 traw = *(const u32x4*)(const void*)(Bg + c * 512 + mm * 32 + quad * 8);
    half8 tf = __builtin_bit_cast(half8, traw);
    const int buf = c & 1;

#pragma unroll
    for (int dh = 0; dh < HB; dh++) {
      const ushort* arow = &slab[buf][(dh + quad) * ROWU];
#pragma unroll
      for (int bt = 0; bt < 4; bt++) {
        const int bidx = ((wave * 4 + bt) * 16 + mm) * 4;
        u32x4 raw;
        if constexpr (S == 4) {
          uint2 lo = *(const uint2*)(const void*)(arow + bidx);
          uint2 hi = *(const uint2*)(const void*)(arow + 1024 + bidx);
          raw = (u32x4){lo.x, lo.y, hi.x, hi.y};
        } else {
          if ((wb & 2) == 0) {
            uint2 lo = *(const uint2*)(const void*)(arow + bidx);
            uint2 hi = *(const uint2*)(const void*)(arow + 1024 + bidx);
            raw = (u32x4){lo.x, lo.y, hi.x, hi.y};
          } else {
            uint c0 = *(const uint*)(const void*)(arow + bidx + 2);
            uint2 md = *(const uint2*)(const void*)(arow + 1024 + bidx);
            uint c1 = *(const uint*)(const void*)(arow + 2048 + bidx);
            raw = (u32x4){c0, md.x, md.y, c1};
          }
        }
        half8 xf = __builtin_bit_cast(half8, raw);
        acc[dh][bt] =
            __builtin_amdgcn_mfma_f32_16x16x32_f16(tf, xf, acc[dh][bt], 0, 0, 0);
      }
    }
  }

  // Epilogue: C/D row m=quad*4+reg = n (co*S+dw); col = mm = batch-in-16.
  const bool is_last = (wb + S >= WO);
#pragma unroll
  for (int dh = 0; dh < HB; dh++)
#pragma unroll
    for (int bt = 0; bt < 4; bt++) {
      const int b = (wave * 4 + bt) * 16 + mm;
      ushort* obase = out + t * oT + d * oD + (h0 + dh) * oH + b * 4;
      f32x4 v = acc[dh][bt];
      if constexpr (S == 4) {
        const int co = quad;
        if (co < COUT) {
          const float bv = bias[co];
          // in-pair force-zero for w >= WO (covers h1 w15, h3 w9..11)
          float r0 = (wb + 0 < WO) ? fmaxf(v[0] + bv, 0.f) : 0.f;
          float r1 = (wb + 1 < WO) ? fmaxf(v[1] + bv, 0.f) : 0.f;
          float r2 = (wb + 2 < WO) ? fmaxf(v[2] + bv, 0.f) : 0.f;
          float r3 = (wb + 3 < WO) ? fmaxf(v[3] + bv, 0.f) : 0.f;
          uint2 pk;
          pk.x = (uint)f2h(r0) | ((uint)f2h(r1) << 16);
          pk.y = (uint)f2h(r2) | ((uint)f2h(r3) << 16);
          *(uint2*)(void*)(obase + co * oC + g0 * 1024) = pk;
          if constexpr (PADEND > PADSTART) {
            if (is_last) {
#pragma unroll
              for (int w = PADSTART; w < PADEND; w += 2)
                *(uint*)(void*)(obase + co * oC + (w >> 2) * 1024 + (w & 3)) =
                    0u;
            }
          }
        }
      } else {  // S == 2: regs (0,1)->co0, (2,3)->co1
        const int co0 = quad * 2, co1 = co0 + 1;
        if (co0 < COUT) {
          const float bv = bias[co0];
          float r0 = fmaxf(v[0] + bv, 0.f), r1 = fmaxf(v[1] + bv, 0.f);
          *(uint*)(void*)(obase + co0 * oC + g0 * 1024 + (wb & 3)) =
              (uint)f2h(r0) | ((uint)f2h(r1) << 16);
        }
        if (co1 < COUT) {
          const float bv = bias[co1];
          float r2 = fmaxf(v[2] + bv, 0.f), r3 = fmaxf(v[3] + bv, 0.f);
          *(uint*)(void*)(obase + co1 * oC + g0 * 1024 + (wb & 3)) =
              (uint)f2h(r2) | ((uint)f2h(r3) << 16);
        }
        if constexpr (PADEND > PADSTART) {
          if (is_last) {
#pragma unroll
            for (int cc = 0; cc < 2; cc++) {
              const int co = quad * 2 + cc;
              if (co < COUT) {
#pragma unroll
                for (int w = PADSTART; w < PADEND; w += 2)
                  *(uint*)(void*)(obase + co * oC + (w >> 2) * 1024 +
                                  (w & 3)) = 0u;
              }
            }
          }
        }
      }
    }
}

// h5 f16 [co][t][d][h][b][4] (= group layout, GOUT=1): u64-coalesced.
__global__ __launch_bounds__(256) void fc1_kernel(
    const ushort* __restrict__ h, const float* __restrict__ w,
    const float* __restrict__ bias, float* __restrict__ out) {
  const int o = blockIdx.x, b = threadIdx.x;
  const float* wr = w + o * 1280;
  float a0 = 0.f, a1 = 0.f, a2 = 0.f, a3 = 0.f;
#pragma unroll 4
  for (int kq = 0; kq < 320; kq++) {
    const uint2 hv = *(const uint2*)(const void*)(h + (kq * 256 + b) * 4);
    a0 = fmaf(h2f((ushort)(hv.x & 0xffffu)), wr[4 * kq + 0], a0);
    a1 = fmaf(h2f((ushort)(hv.x >> 16)), wr[4 * kq + 1], a1);
    a2 = fmaf(h2f((ushort)(hv.y & 0xffffu)), wr[4 * kq + 2], a2);
    a3 = fmaf(h2f((ushort)(hv.y >> 16)), wr[4 * kq + 3], a3);
  }
  float acc = (a0 + a1) + (a2 + a3) + bias[o];
  out[o * BATCH + b] = acc > 0.f ? acc : 0.f;
}

__global__ __launch_bounds__(256) void fc2_kernel(
    const float* __restrict__ r, const float* __restrict__ w,
    const float* __restrict__ bias, float* __restrict__ out) {
  const int b = threadIdx.x;
  float acc = bias[0];
#pragma unroll
  for (int o = 0; o < 33; o++) acc = fmaf(r[o * BATCH + b], w[o], acc);
  out[b] = 1.f / (1.f + expf(-acc));
}

extern "C" void kernel_launch(void* const* d_in, const int* in_sizes, int n_in,
                              void* d_out, int out_size, void* d_ws,
                              size_t ws_size, hipStream_t stream) {
  const float* x    = (const float*)d_in[0];
  const float* w1   = (const float*)d_in[1];
  const float* b1   = (const float*)d_in[2];
  const float* w2   = (const float*)d_in[3];
  const float* b2   = (const float*)d_in[4];
  const float* w3   = (const float*)d_in[5];
  const float* b3   = (const float*)d_in[6];
  const float* w4   = (const float*)d_in[7];
  const float* b4   = (const float*)d_in[8];
  const float* w5   = (const float*)d_in[9];
  const float* b5   = (const float*)d_in[10];
  const float* fc1w = (const float*)d_in[11];
  const float* fc1b = (const float*)d_in[12];
  const float* fc2w = (const float*)d_in[13];
  const float* fc2b = (const float*)d_in[14];
  float* out = (float*)d_out;

  // Workspace (u16 units), group layout [c][t][d][h][g][b][4]:
  // R0: xt 29,859,840 (G=5) / h2 21,233,664 (G=4) / h4 3,317,760 (G=3)
  // R1: h1 41,472,000 (G=4) / h3  8,957,952 (G=3) / h5   327,680 (G=1)
  // Staging may overread ~6KB past tensor ends (clamped rows / extra GW slot)
  // -> margins between regions; never frag-read, harmless if garbage.
  ushort* wsu = (ushort*)d_ws;
  ushort* R0 = wsu;
  ushort* R1 = wsu + 29900000;
  ushort* Bgb = wsu + 71400000;      // 221*512 = 113,152 u16
  float* fo = (float*)(wsu + 71520000);

  ushort* xt = R0;
  ushort* h1 = R1;
  ushort* h2 = R0;
  ushort* h3 = R1;
  ushort* h4 = R0;
  ushort* h5 = R1;

  ushort* B1 = Bgb;                 // 16 chunks
  ushort* B2 = Bgb + 16 * 512;      // 48
  ushort* B3 = Bgb + 64 * 512;      // 48
  ushort* B4 = Bgb + 112 * 512;     // 64
  ushort* B5 = Bgb + 176 * 512;     // 45

  build_b<1, 3, 4, 4><<<16, 256, 0, stream>>>(w1, B1);
  build_b<3, 3, 4, 4><<<48, 256, 0, stream>>>(w2, B2);
  build_b<3, 4, 4, 4><<<48, 256, 0, stream>>>(w3, B3);
  build_b<4, 5, 4, 2><<<64, 256, 0, stream>>>(w4, B4);
  build_b<5, 5, 3, 2><<<45, 256, 0, stream>>>(w5, B5);

  // 52488 w-pairs / 64 per tile = 821 tiles (last partial), 4 b-chunks
  transpose_kernel<<<dim3(821, 4), 256, 0, stream>>>(x, (uint*)xt);

  // <CIN,COUT,KK,TI,GIN,GOUT,S,HB,PADSTART,PADEND> grid(x=wt*HTILES+ht,y=d,z=t)
  conv_mfma<1, 3, 4, 18, 5, 4, 4, 5, 0, 0>
      <<<dim3(12, 15, 15), 256, 0, stream>>>(xt, B1, b1, h1);
  conv_mfma<3, 3, 4, 15, 4, 4, 4, 4, 12, 16>
      <<<dim3(9, 12, 12), 256, 0, stream>>>(h1, B2, b2, h2);
  conv_mfma<3, 4, 4, 12, 4, 3, 4, 3, 0, 0>
      <<<dim3(9, 9, 9), 256, 0, stream>>>(h2, B3, b3, h3);
  conv_mfma<4, 5, 4, 9, 3, 3, 2, 2, 6, 12>
      <<<dim3(9, 6, 6), 256, 0, stream>>>(h3, B4, b4, h4);
  conv_mfma<5, 5, 3, 6, 3, 1, 2, 2, 0, 0>
      <<<dim3(4, 4, 4), 256, 0, stream>>>(h4, B5, b5, h5);

  fc1_kernel<<<33, 256, 0, stream>>>(h5, fc1w, fc1b, fo);
  fc2_kernel<<<1, 256, 0, stream>>>(fo, fc2w, fc2b, out);
}

// Round 10
// 721.649 us; speedup vs baseline: 1.3770x; 1.0672x over previous
//
#include <hip/hip_runtime.h>
#include <math.h>

#define BATCH 256
typedef unsigned int uint;
typedef unsigned short ushort;
typedef _Float16 half8 __attribute__((ext_vector_type(8)));
typedef float f32x4 __attribute__((ext_vector_type(4)));
typedef uint u32x4 __attribute__((ext_vector_type(4)));

#define GLOBAL_AS __attribute__((address_space(1)))
#define LDS_AS __attribute__((address_space(3)))

__device__ __forceinline__ ushort f2h(float f) {
  _Float16 h = (_Float16)f;
  return __builtin_bit_cast(ushort, h);
}
__device__ __forceinline__ float h2f(ushort u) {
  return (float)__builtin_bit_cast(_Float16, u);
}

// Counted vmcnt wait (T4). "memory" clobber keeps ds_reads from hoisting
// above; sched_barrier(0) guards against rule-18 style reordering.
template <int N>
__device__ __forceinline__ void waitv() {
  if constexpr (N == 0) {
    asm volatile("s_waitcnt vmcnt(0)" ::: "memory");
  } else if constexpr (N == 7) {
    asm volatile("s_waitcnt vmcnt(7)" ::: "memory");
  } else if constexpr (N == 9) {
    asm volatile("s_waitcnt vmcnt(9)" ::: "memory");
  } else if constexpr (N == 10) {
    asm volatile("s_waitcnt vmcnt(10)" ::: "memory");
  } else {
    static_assert(N == 0 || N == 7 || N == 9 || N == 10, "add literal");
  }
  __builtin_amdgcn_sched_barrier(0);
}

// x fp32 [256][P=18^4] -> xt group layout [sh=(t,d,h)][g=5][b=256][4w] u16.
// 64x64 u32-tile LDS transpose: coalesced 512B global reads AND uint2 writes.
__global__ __launch_bounds__(256) void transpose_kernel(
    const float* __restrict__ x, uint* __restrict__ xt) {
  __shared__ uint tile[65][65];
  const int P = 104976, NPP = 52488;
  const int pp0 = blockIdx.x * 64, b0 = blockIdx.y * 64;
  const int tx = threadIdx.x & 63, ty = threadIdx.x >> 6;
  for (int r = 0; r < 64; r += 4) {
    const int bl = ty + r, pp = pp0 + tx;
    if (pp < NPP) {
      const float2 v = *(const float2*)(x + (size_t)(b0 + bl) * P + 2 * pp);
      tile[tx][bl] = (uint)f2h(v.x) | ((uint)f2h(v.y) << 16);
    }
  }
  if (threadIdx.x < 64 && pp0 + 64 < NPP) {
    const int bl = threadIdx.x;
    const float2 v =
        *(const float2*)(x + (size_t)(b0 + bl) * P + 2 * (pp0 + 64));
    tile[64][bl] = (uint)f2h(v.x) | ((uint)f2h(v.y) << 16);
  }
  __syncthreads();
  for (int r = ty; r < 64; r += 4) {
    const int pp = pp0 + r;
    if (pp >= NPP) break;
    const int wp = pp % 9, sh = pp / 9;
    if (wp & 1) continue;
    uint2 o;
    o.x = tile[r][tx];
    o.y = (wp == 8) ? 0u : tile[r + 1][tx];
    *(uint2*)(xt + (size_t)(sh * 5 + (wp >> 1)) * 512 + (b0 + tx) * 2) = o;
  }
}

// Block-Toeplitz table: Bg[chunk][n=16][k=32] f16, chunk=(ci*KK+kt)*KK+kd,
// k=kh*8+wi, n=co*S+dw. B[k][n] = w[co][ci][kt][kd][kh][wi-dw] if valid else 0.
template <int CIN, int COUT, int KK, int S>
__global__ __launch_bounds__(256) void build_b(
    const float* __restrict__ w, ushort* __restrict__ Bg) {
  const int chunk = blockIdx.x;
  const int kd = chunk % KK, kt = (chunk / KK) % KK, ci = chunk / (KK * KK);
  for (int e = threadIdx.x; e < 512; e += 256) {
    int n = e >> 5, k = e & 31;
    int kh = k >> 3, wi = k & 7;
    int co = n / S, dw = n % S;
    int kw = wi - dw;
    float v = 0.f;
    if (co < COUT && kh < KK && kw >= 0 && kw < KK)
      v = w[((((co * CIN + ci) * KK + kt) * KK + kd) * KK + kh) * KK + kw];
    Bg[chunk * 512 + n * 32 + k] = f2h(v);
  }
}

// Barrier-free per-wave MFMA conv (S=4 layers). Each wave owns batches
// [wave*64, wave*64+64) -> fully independent: private LDS slab, per-wave
// global_load_lds staging (x rows: lanes = [g half][b-pair]; Bg: permuted
// source so read-back is linear lane*16B), depth-2 pipeline with counted
// s_waitcnt vmcnt(CH). NO __syncthreads anywhere -> no vmcnt(0) drains.
template <int CIN, int COUT, int KK, int TI, int GIN, int GOUT, int HB,
          int PADSTART, int PADEND>
__global__ __launch_bounds__(256) void conv_wave(
    const ushort* __restrict__ xin, const ushort* __restrict__ Bg,
    const float* __restrict__ bias, ushort* __restrict__ out) {
  constexpr int S = 4;
  constexpr int WO = TI - KK + 1;
  constexpr int HTILES = WO / HB;
  constexpr int NC = CIN * KK * KK;
  constexpr int RS = 4 + HB - 1;   // staged h-rows (KHP=4); KK=4 -> no clamp
  constexpr int CH = RS + 1;       // loads per chunk (RS x-rows + 1 Bg)
  constexpr int sH = GIN * 1024, sD = TI * sH, sT = TI * sD, sC = TI * sT;
  constexpr int oH = GOUT * 1024, oD = WO * oH, oT = WO * oD, oC = WO * oT;

  __shared__ ushort slab[4][2][CH * 512];  // [wave][buf]; 1KB per slot

  const int ht = blockIdx.x % HTILES;
  const int wt = blockIdx.x / HTILES;
  const int d = blockIdx.y, t = blockIdx.z;
  const int h0 = ht * HB, wb = wt * S;
  const int g0 = wb >> 2;

  const int tid = threadIdx.x;
  const int wave = tid >> 6, lane = tid & 63;
  const int quad = lane >> 4, mm = lane & 15;

  // x row src: lane covers (g = lane>>5, batches wave*64 + (lane&31)*2 ..+1)
  const int xsrc = (lane >> 5) * 1024 + wave * 256 + (lane & 31) * 8;
  // Bg src permuted so LDS[lane*8 u16] = Bg[mm*32 + quad*8] (linear read-back)
  const int bsrc = mm * 32 + quad * 8;

  f32x4 acc[HB][4];
#pragma unroll
  for (int dh = 0; dh < HB; dh++)
#pragma unroll
    for (int bt = 0; bt < 4; bt++) acc[dh][bt] = (f32x4){0.f, 0.f, 0.f, 0.f};

  auto stage = [&](int c, int buf) {
    const int kd = c % KK, kt2 = (c / KK) % KK, ci = c / (KK * KK);
    const ushort* base =
        xin + ci * sC + (t + kt2) * sT + (d + kd) * sD + h0 * sH + g0 * 1024;
    ushort* l = &slab[wave][buf][0];
#pragma unroll
    for (int r = 0; r < RS; r++)
      __builtin_amdgcn_global_load_lds(
          (const GLOBAL_AS uint*)(const void*)(base + r * sH + xsrc),
          (LDS_AS uint*)(void*)(l + r * 512), 16, 0, 0);
    __builtin_amdgcn_global_load_lds(
        (const GLOBAL_AS uint*)(const void*)(Bg + c * 512 + bsrc),
        (LDS_AS uint*)(void*)(l + RS * 512), 16, 0, 0);
  };

  stage(0, 0);

  for (int c = 0; c < NC; c++) {
    if (c + 1 < NC) {
      stage(c + 1, (c + 1) & 1);  // buf (c+1)&1 last read at iter c-1: safe
      waitv<CH>();                // chunk c complete; c+1 stays in flight
    } else {
      waitv<0>();
    }
    const ushort* wsl = &slab[wave][c & 1][0];
    u32x4 traw = *(const u32x4*)(const void*)(wsl + RS * 512 + lane * 8);
    half8 tf = __builtin_bit_cast(half8, traw);
#pragma unroll
    for (int dh = 0; dh < HB; dh++) {
      const ushort* arow = wsl + (dh + quad) * 512;
#pragma unroll
      for (int bt = 0; bt < 4; bt++) {
        const int bb = bt * 16 + mm;
        uint2 lo = *(const uint2*)(const void*)(arow + bb * 4);
        uint2 hi = *(const uint2*)(const void*)(arow + 256 + bb * 4);
        half8 xf = __builtin_bit_cast(half8, (u32x4){lo.x, lo.y, hi.x, hi.y});
        acc[dh][bt] =
            __builtin_amdgcn_mfma_f32_16x16x32_f16(tf, xf, acc[dh][bt], 0, 0, 0);
      }
    }
  }

  // Epilogue: C/D row m=quad*4+reg = n (co*S+dw); col = mm.
  const bool is_last = (wb + S >= WO);
  const int co = quad;
#pragma unroll
  for (int dh = 0; dh < HB; dh++)
#pragma unroll
    for (int bt = 0; bt < 4; bt++) {
      const int b = wave * 64 + bt * 16 + mm;
      ushort* obase = out + t * oT + d * oD + (h0 + dh) * oH + b * 4;
      f32x4 v = acc[dh][bt];
      if (co < COUT) {
        const float bv = bias[co];
        float r0 = (wb + 0 < WO) ? fmaxf(v[0] + bv, 0.f) : 0.f;
        float r1 = (wb + 1 < WO) ? fmaxf(v[1] + bv, 0.f) : 0.f;
        float r2 = (wb + 2 < WO) ? fmaxf(v[2] + bv, 0.f) : 0.f;
        float r3 = (wb + 3 < WO) ? fmaxf(v[3] + bv, 0.f) : 0.f;
        uint2 pk;
        pk.x = (uint)f2h(r0) | ((uint)f2h(r1) << 16);
        pk.y = (uint)f2h(r2) | ((uint)f2h(r3) << 16);
        *(uint2*)(void*)(obase + co * oC + g0 * 1024) = pk;
        if constexpr (PADEND > PADSTART) {
          if (is_last) {
#pragma unroll
            for (int w = PADSTART; w < PADEND; w += 2)
              *(uint*)(void*)(obase + co * oC + (w >> 2) * 1024 + (w & 3)) = 0u;
          }
        }
      }
    }
}

// Block-cooperative barrier version, retained for S=2 layers (L4, L5).
template <int CIN, int COUT, int KK, int TI, int GIN, int GOUT, int S, int HB,
          int PADSTART, int PADEND>
__global__ __launch_bounds__(256) void conv_mfma(
    const ushort* __restrict__ xin, const ushort* __restrict__ Bg,
    const float* __restrict__ bias, ushort* __restrict__ out) {
  constexpr int WO = TI - KK + 1;
  constexpr int HTILES = WO / HB;
  constexpr int NC = CIN * KK * KK;
  constexpr int RS = 4 + HB - 1;
  constexpr int GW = (S == 4 ? 2 : 3);
  constexpr int ROWU = GW * 1024;
  constexpr int PROW = GW * 2;
  constexpr int sH = GIN * 1024, sD = TI * sH, sT = TI * sD, sC = TI * sT;
  constexpr int oH = GOUT * 1024, oD = WO * oH, oT = WO * oD, oC = WO * oT;

  __shared__ ushort slab[2][RS * ROWU];

  const int ht = blockIdx.x % HTILES;
  const int wt = blockIdx.x / HTILES;
  const int d = blockIdx.y, t = blockIdx.z;
  const int h0 = ht * HB, wb = wt * S;
  const int g0 = wb >> 2;

  const int tid = threadIdx.x;
  const int wave = tid >> 6, lane = tid & 63;
  const int quad = lane >> 4, mm = lane & 15;

  f32x4 acc[HB][4];
#pragma unroll
  for (int dh = 0; dh < HB; dh++)
#pragma unroll
    for (int bt = 0; bt < 4; bt++) acc[dh][bt] = (f32x4){0.f, 0.f, 0.f, 0.f};

  auto stage = [&](int c, int buf) {
    const int kd = c % KK, kt2 = (c / KK) % KK, ci = c / (KK * KK);
    const ushort* base =
        xin + ci * sC + (t + kt2) * sT + (d + kd) * sD + g0 * 1024;
    for (int r = wave; r < RS; r += 4) {
      int row = h0 + r;
      if (row > TI - 1) row = TI - 1;  // KK=3 tail rows (zero-weight) clamp
      const ushort* g = base + row * sH;
      ushort* l = &slab[buf][r * ROWU];
#pragma unroll
      for (int p = 0; p < PROW; p++) {
        __builtin_amdgcn_global_load_lds(
            (const GLOBAL_AS uint*)(const void*)(g + p * 512 + lane * 8),
            (LDS_AS uint*)(void*)(l + p * 512), 16, 0, 0);
      }
    }
  };

  stage(0, 0);

  for (int c = 0; c < NC; c++) {
    __syncthreads();
    if (c + 1 < NC) stage(c + 1, (c + 1) & 1);

    u32x4 traw = *(const u32x4*)(const void*)(Bg + c * 512 + mm * 32 + quad * 8);
    half8 tf = __builtin_bit_cast(half8, traw);
    const int buf = c & 1;

#pragma unroll
    for (int dh = 0; dh < HB; dh++) {
      const ushort* arow = &slab[buf][(dh + quad) * ROWU];
#pragma unroll
      for (int bt = 0; bt < 4; bt++) {
        const int bidx = ((wave * 4 + bt) * 16 + mm) * 4;
        u32x4 raw;
        if ((wb & 2) == 0) {
          uint2 lo = *(const uint2*)(const void*)(arow + bidx);
          uint2 hi = *(const uint2*)(const void*)(arow + 1024 + bidx);
          raw = (u32x4){lo.x, lo.y, hi.x, hi.y};
        } else {
          uint c0 = *(const uint*)(const void*)(arow + bidx + 2);
          uint2 md = *(const uint2*)(const void*)(arow + 1024 + bidx);
          uint c1 = *(const uint*)(const void*)(arow + 2048 + bidx);
          raw = (u32x4){c0, md.x, md.y, c1};
        }
        half8 xf = __builtin_bit_cast(half8, raw);
        acc[dh][bt] =
            __builtin_amdgcn_mfma_f32_16x16x32_f16(tf, xf, acc[dh][bt], 0, 0, 0);
      }
    }
  }

  const bool is_last = (wb + S >= WO);
#pragma unroll
  for (int dh = 0; dh < HB; dh++)
#pragma unroll
    for (int bt = 0; bt < 4; bt++) {
      const int b = (wave * 4 + bt) * 16 + mm;
      ushort* obase = out + t * oT + d * oD + (h0 + dh) * oH + b * 4;
      f32x4 v = acc[dh][bt];
      const int co0 = quad * 2, co1 = co0 + 1;
      if (co0 < COUT) {
        const float bv = bias[co0];
        float r0 = fmaxf(v[0] + bv, 0.f), r1 = fmaxf(v[1] + bv, 0.f);
        *(uint*)(void*)(obase + co0 * oC + g0 * 1024 + (wb & 3)) =
            (uint)f2h(r0) | ((uint)f2h(r1) << 16);
      }
      if (co1 < COUT) {
        const float bv = bias[co1];
        float r2 = fmaxf(v[2] + bv, 0.f), r3 = fmaxf(v[3] + bv, 0.f);
        *(uint*)(void*)(obase + co1 * oC + g0 * 1024 + (wb & 3)) =
            (uint)f2h(r2) | ((uint)f2h(r3) << 16);
      }
      if constexpr (PADEND > PADSTART) {
        if (is_last) {
#pragma unroll
          for (int cc = 0; cc < 2; cc++) {
            const int co = quad * 2 + cc;
            if (co < COUT) {
#pragma unroll
              for (int w = PADSTART; w < PADEND; w += 2)
                *(uint*)(void*)(obase + co * oC + (w >> 2) * 1024 + (w & 3)) =
                    0u;
            }
          }
        }
      }
    }
}

// h5 f16 [co][t][d][h][b][4] (= group layout, GOUT=1): u64-coalesced.
__global__ __launch_bounds__(256) void fc1_kernel(
    const ushort* __restrict__ h, const float* __restrict__ w,
    const float* __restrict__ bias, float* __restrict__ out) {
  const int o = blockIdx.x, b = threadIdx.x;
  const float* wr = w + o * 1280;
  float a0 = 0.f, a1 = 0.f, a2 = 0.f, a3 = 0.f;
#pragma unroll 4
  for (int kq = 0; kq < 320; kq++) {
    const uint2 hv = *(const uint2*)(const void*)(h + (kq * 256 + b) * 4);
    a0 = fmaf(h2f((ushort)(hv.x & 0xffffu)), wr[4 * kq + 0], a0);
    a1 = fmaf(h2f((ushort)(hv.x >> 16)), wr[4 * kq + 1], a1);
    a2 = fmaf(h2f((ushort)(hv.y & 0xffffu)), wr[4 * kq + 2], a2);
    a3 = fmaf(h2f((ushort)(hv.y >> 16)), wr[4 * kq + 3], a3);
  }
  float acc = (a0 + a1) + (a2 + a3) + bias[o];
  out[o * BATCH + b] = acc > 0.f ? acc : 0.f;
}

__global__ __launch_bounds__(256) void fc2_kernel(
    const float* __restrict__ r, const float* __restrict__ w,
    const float* __restrict__ bias, float* __restrict__ out) {
  const int b = threadIdx.x;
  float acc = bias[0];
#pragma unroll
  for (int o = 0; o < 33; o++) acc = fmaf(r[o * BATCH + b], w[o], acc);
  out[b] = 1.f / (1.f + expf(-acc));
}

extern "C" void kernel_launch(void* const* d_in, const int* in_sizes, int n_in,
                              void* d_out, int out_size, void* d_ws,
                              size_t ws_size, hipStream_t stream) {
  const float* x    = (const float*)d_in[0];
  const float* w1   = (const float*)d_in[1];
  const float* b1   = (const float*)d_in[2];
  const float* w2   = (const float*)d_in[3];
  const float* b2   = (const float*)d_in[4];
  const float* w3   = (const float*)d_in[5];
  const float* b3   = (const float*)d_in[6];
  const float* w4   = (const float*)d_in[7];
  const float* b4   = (const float*)d_in[8];
  const float* w5   = (const float*)d_in[9];
  const float* b5   = (const float*)d_in[10];
  const float* fc1w = (const float*)d_in[11];
  const float* fc1b = (const float*)d_in[12];
  const float* fc2w = (const float*)d_in[13];
  const float* fc2b = (const float*)d_in[14];
  float* out = (float*)d_out;

  // Workspace (u16 units), group layout [c][t][d][h][g][b][4]:
  // R0: xt 29,859,840 (G=5) / h2 21,233,664 (G=4) / h4 3,317,760 (G=3)
  // R1: h1 41,472,000 (G=4) / h3  8,957,952 (G=3) / h5   327,680 (G=1)
  ushort* wsu = (ushort*)d_ws;
  ushort* R0 = wsu;
  ushort* R1 = wsu + 29900000;
  ushort* Bgb = wsu + 71400000;      // 221*512 = 113,152 u16
  float* fo = (float*)(wsu + 71520000);

  ushort* xt = R0;
  ushort* h1 = R1;
  ushort* h2 = R0;
  ushort* h3 = R1;
  ushort* h4 = R0;
  ushort* h5 = R1;

  ushort* B1 = Bgb;                 // 16 chunks
  ushort* B2 = Bgb + 16 * 512;      // 48
  ushort* B3 = Bgb + 64 * 512;      // 48
  ushort* B4 = Bgb + 112 * 512;     // 64
  ushort* B5 = Bgb + 176 * 512;     // 45

  build_b<1, 3, 4, 4><<<16, 256, 0, stream>>>(w1, B1);
  build_b<3, 3, 4, 4><<<48, 256, 0, stream>>>(w2, B2);
  build_b<3, 4, 4, 4><<<48, 256, 0, stream>>>(w3, B3);
  build_b<4, 5, 4, 2><<<64, 256, 0, stream>>>(w4, B4);
  build_b<5, 5, 3, 2><<<45, 256, 0, stream>>>(w5, B5);

  transpose_kernel<<<dim3(821, 4), 256, 0, stream>>>(x, (uint*)xt);

  // Barrier-free per-wave convs (S=4):
  // <CIN,COUT,KK,TI,GIN,GOUT,HB,PADS,PADE>  grid(x = wt*HTILES+ht, y=d, z=t)
  conv_wave<1, 3, 4, 18, 5, 4, 5, 0, 0>     // CH=9,  LDS 72KB, 2 blk/CU
      <<<dim3(12, 15, 15), 256, 0, stream>>>(xt, B1, b1, h1);
  conv_wave<3, 3, 4, 15, 4, 4, 6, 12, 16>   // CH=10, LDS 80KB, 2 blk/CU
      <<<dim3(6, 12, 12), 256, 0, stream>>>(h1, B2, b2, h2);
  conv_wave<3, 4, 4, 12, 4, 3, 3, 0, 0>     // CH=7,  LDS 56KB, 2 blk/CU
      <<<dim3(9, 9, 9), 256, 0, stream>>>(h2, B3, b3, h3);

  // Small S=2 layers on the proven barrier template:
  conv_mfma<4, 5, 4, 9, 3, 3, 2, 2, 6, 12>
      <<<dim3(9, 6, 6), 256, 0, stream>>>(h3, B4, b4, h4);
  conv_mfma<5, 5, 3, 6, 3, 1, 2, 2, 0, 0>
      <<<dim3(4, 4, 4), 256, 0, stream>>>(h4, B5, b5, h5);

  fc1_kernel<<<33, 256, 0, stream>>>(h5, fc1w, fc1b, fo);
  fc2_kernel<<<1, 256, 0, stream>>>(fo, fc2w, fc2b, out);
}

// Round 12
// 657.032 us; speedup vs baseline: 1.5124x; 1.0983x over previous
//
#include <hip/hip_runtime.h>
#include <math.h>

#define BATCH 256
typedef unsigned int uint;
typedef unsigned short ushort;
typedef _Float16 half8 __attribute__((ext_vector_type(8)));
typedef float f32x4 __attribute__((ext_vector_type(4)));
typedef uint u32x4 __attribute__((ext_vector_type(4)));

#define GLOBAL_AS __attribute__((address_space(1)))
#define LDS_AS __attribute__((address_space(3)))

__device__ __forceinline__ ushort f2h(float f) {
  _Float16 h = (_Float16)f;
  return __builtin_bit_cast(ushort, h);
}
__device__ __forceinline__ float h2f(ushort u) {
  return (float)__builtin_bit_cast(_Float16, u);
}

// Counted vmcnt wait (T4). "memory" clobber orders memory ops across it;
// sched_barrier(0) pins instruction motion (rule-18 guard).
template <int N>
__device__ __forceinline__ void waitv() {
  if constexpr (N == 0) {
    asm volatile("s_waitcnt vmcnt(0)" ::: "memory");
  } else if constexpr (N == 7) {
    asm volatile("s_waitcnt vmcnt(7)" ::: "memory");
  } else if constexpr (N == 9) {
    asm volatile("s_waitcnt vmcnt(9)" ::: "memory");
  } else if constexpr (N == 10) {
    asm volatile("s_waitcnt vmcnt(10)" ::: "memory");
  } else {
    static_assert(N == 0 || N == 7 || N == 9 || N == 10, "add literal");
  }
  __builtin_amdgcn_sched_barrier(0);
}

// Bijective chunked XCD swizzle (T1, m204): consecutive logical blocks land
// on the same XCD so same-(t,d) blocks share one L2's input slabs.
template <int NWG>
__device__ __forceinline__ int xcd_swz(int bid) {
  constexpr int Q = NWG / 8, R = NWG % 8;
  const int x = bid & 7, i = bid >> 3;
  return (x < R ? x * (Q + 1) : R * (Q + 1) + (x - R) * Q) + i;
}

// x fp32 [256][P=18^4] -> xt group layout [sh=(t,d,h)][g=5][b=256][4w] u16.
// 64x64 u32-tile LDS transpose: coalesced 512B global reads AND uint2 writes.
__global__ __launch_bounds__(256) void transpose_kernel(
    const float* __restrict__ x, uint* __restrict__ xt) {
  __shared__ uint tile[65][65];
  const int P = 104976, NPP = 52488;
  const int pp0 = blockIdx.x * 64, b0 = blockIdx.y * 64;
  const int tx = threadIdx.x & 63, ty = threadIdx.x >> 6;
  for (int r = 0; r < 64; r += 4) {
    const int bl = ty + r, pp = pp0 + tx;
    if (pp < NPP) {
      const float2 v = *(const float2*)(x + (size_t)(b0 + bl) * P + 2 * pp);
      tile[tx][bl] = (uint)f2h(v.x) | ((uint)f2h(v.y) << 16);
    }
  }
  if (threadIdx.x < 64 && pp0 + 64 < NPP) {
    const int bl = threadIdx.x;
    const float2 v =
        *(const float2*)(x + (size_t)(b0 + bl) * P + 2 * (pp0 + 64));
    tile[64][bl] = (uint)f2h(v.x) | ((uint)f2h(v.y) << 16);
  }
  __syncthreads();
  for (int r = ty; r < 64; r += 4) {
    const int pp = pp0 + r;
    if (pp >= NPP) break;
    const int wp = pp % 9, sh = pp / 9;
    if (wp & 1) continue;
    uint2 o;
    o.x = tile[r][tx];
    o.y = (wp == 8) ? 0u : tile[r + 1][tx];
    *(uint2*)(xt + (size_t)(sh * 5 + (wp >> 1)) * 512 + (b0 + tx) * 2) = o;
  }
}

// Block-Toeplitz table: Bg[chunk][n=16][k=32] f16, chunk=(ci*KK+kt)*KK+kd,
// k=kh*8+wi, n=co*S+dw. B[k][n] = w[co][ci][kt][kd][kh][wi-dw] if valid else 0.
template <int CIN, int COUT, int KK, int S>
__global__ __launch_bounds__(256) void build_b(
    const float* __restrict__ w, ushort* __restrict__ Bg) {
  const int chunk = blockIdx.x;
  const int kd = chunk % KK, kt = (chunk / KK) % KK, ci = chunk / (KK * KK);
  for (int e = threadIdx.x; e < 512; e += 256) {
    int n = e >> 5, k = e & 31;
    int kh = k >> 3, wi = k & 7;
    int co = n / S, dw = n % S;
    int kw = wi - dw;
    float v = 0.f;
    if (co < COUT && kh < KK && kw >= 0 && kw < KK)
      v = w[((((co * CIN + ci) * KK + kt) * KK + kd) * KK + kh) * KK + kw];
    Bg[chunk * 512 + n * 32 + k] = f2h(v);
  }
}

// Barrier-free per-wave MFMA conv (S=4 layers). Per-wave private LDS slab,
// global_load_lds x-staging, tf loaded DIRECT global->VGPR (dwordx4, Bg is
// L2-resident), depth-2 pipeline with counted vmcnt. Per-chunk VMEM ops =
// RS x-rows + 1 tf = CH, so waitv<CH> completes chunk c with c+1 in flight.
// NO __syncthreads anywhere. 1D grid with XCD swizzle.
template <int CIN, int COUT, int KK, int TI, int GIN, int GOUT, int HB,
          int PADSTART, int PADEND>
__global__ __launch_bounds__(256) void conv_wave(
    const ushort* __restrict__ xin, const ushort* __restrict__ Bg,
    const float* __restrict__ bias, ushort* __restrict__ out) {
  constexpr int S = 4;
  constexpr int WO = TI - KK + 1;
  constexpr int HTILES = WO / HB;
  constexpr int WTILES = (WO + S - 1) / S;
  constexpr int GX = HTILES * WTILES;
  constexpr int NWG = GX * WO * WO;
  constexpr int NC = CIN * KK * KK;
  static_assert(NC % 2 == 0, "pair-unrolled chunk loop needs even NC");
  constexpr int RS = 4 + HB - 1;   // staged h-rows (KHP=4); KK=4 -> no clamp
  constexpr int CH = RS + 1;       // VMEM ops per chunk (RS x-rows + 1 tf)
  constexpr int sH = GIN * 1024, sD = TI * sH, sT = TI * sD, sC = TI * sT;
  constexpr int oH = GOUT * 1024, oD = WO * oH, oT = WO * oD, oC = WO * oT;

  __shared__ ushort slab[4][2][RS * 512];  // [wave][buf]; 1KB per h-row

  const int wg = xcd_swz<NWG>(blockIdx.x);
  const int xb = wg % GX;
  const int d = (wg / GX) % WO;
  const int t = wg / (GX * WO);
  const int ht = xb % HTILES, wt = xb / HTILES;
  const int h0 = ht * HB, wb = wt * S;
  const int g0 = wb >> 2;

  const int tid = threadIdx.x;
  const int wave = tid >> 6, lane = tid & 63;
  const int quad = lane >> 4, mm = lane & 15;

  // x row src: lane covers (g = lane>>5, batches wave*64 + (lane&31)*2 ..+1)
  const int xsrc = (lane >> 5) * 1024 + wave * 256 + (lane & 31) * 8;
  const int bsrc = mm * 32 + quad * 8;  // per-lane 16B tf fragment in Bg

  f32x4 acc[HB][4];
#pragma unroll
  for (int dh = 0; dh < HB; dh++)
#pragma unroll
    for (int bt = 0; bt < 4; bt++) acc[dh][bt] = (f32x4){0.f, 0.f, 0.f, 0.f};

  auto stage = [&](int c, int buf) {
    const int kd = c % KK, kt2 = (c / KK) % KK, ci = c / (KK * KK);
    const ushort* base =
        xin + ci * sC + (t + kt2) * sT + (d + kd) * sD + h0 * sH + g0 * 1024;
    ushort* l = &slab[wave][buf][0];
#pragma unroll
    for (int r = 0; r < RS; r++)
      __builtin_amdgcn_global_load_lds(
          (const GLOBAL_AS uint*)(const void*)(base + r * sH + xsrc),
          (LDS_AS uint*)(void*)(l + r * 512), 16, 0, 0);
  };

  auto load_tf = [&](int c) -> u32x4 {
    return *(const u32x4*)(const void*)(Bg + c * 512 + bsrc);
  };

  auto compute = [&](int buf, u32x4 traw) {
    half8 tf = __builtin_bit_cast(half8, traw);
    const ushort* wsl = &slab[wave][buf][0];
#pragma unroll
    for (int dh = 0; dh < HB; dh++) {
      const ushort* arow = wsl + (dh + quad) * 512;
#pragma unroll
      for (int bt = 0; bt < 4; bt++) {
        const int bb = bt * 16 + mm;
        uint2 lo = *(const uint2*)(const void*)(arow + bb * 4);
        uint2 hi = *(const uint2*)(const void*)(arow + 256 + bb * 4);
        half8 xf = __builtin_bit_cast(half8, (u32x4){lo.x, lo.y, hi.x, hi.y});
        acc[dh][bt] =
            __builtin_amdgcn_mfma_f32_16x16x32_f16(tf, xf, acc[dh][bt], 0, 0, 0);
      }
    }
  };

  stage(0, 0);
  u32x4 tfA = load_tf(0);
  u32x4 tfB;

  for (int c = 0; c < NC; c += 2) {
    // prefetch odd chunk c+1 (always exists: NC even)
    tfB = load_tf(c + 1);
    stage(c + 1, 1);
    waitv<CH>();          // chunk c (x rows + tfA) landed; c+1 in flight
    compute(0, tfA);
    __builtin_amdgcn_sched_barrier(0);  // pin buf0 ds_reads before next stage
    if (c + 2 < NC) {
      tfA = load_tf(c + 2);
      stage(c + 2, 0);
      waitv<CH>();        // chunk c+1 landed; c+2 in flight
    } else {
      waitv<0>();
    }
    compute(1, tfB);
    __builtin_amdgcn_sched_barrier(0);  // pin buf1 ds_reads before next stage
  }

  // Epilogue: C/D row m=quad*4+reg = n (co*S+dw); col = mm.
  const bool is_last = (wb + S >= WO);
  const int co = quad;
#pragma unroll
  for (int dh = 0; dh < HB; dh++)
#pragma unroll
    for (int bt = 0; bt < 4; bt++) {
      const int b = wave * 64 + bt * 16 + mm;
      ushort* obase = out + t * oT + d * oD + (h0 + dh) * oH + b * 4;
      f32x4 v = acc[dh][bt];
      if (co < COUT) {
        const float bv = bias[co];
        float r0 = (wb + 0 < WO) ? fmaxf(v[0] + bv, 0.f) : 0.f;
        float r1 = (wb + 1 < WO) ? fmaxf(v[1] + bv, 0.f) : 0.f;
        float r2 = (wb + 2 < WO) ? fmaxf(v[2] + bv, 0.f) : 0.f;
        float r3 = (wb + 3 < WO) ? fmaxf(v[3] + bv, 0.f) : 0.f;
        uint2 pk;
        pk.x = (uint)f2h(r0) | ((uint)f2h(r1) << 16);
        pk.y = (uint)f2h(r2) | ((uint)f2h(r3) << 16);
        *(uint2*)(void*)(obase + co * oC + g0 * 1024) = pk;
        if constexpr (PADEND > PADSTART) {
          if (is_last) {
#pragma unroll
            for (int w = PADSTART; w < PADEND; w += 2)
              *(uint*)(void*)(obase + co * oC + (w >> 2) * 1024 + (w & 3)) = 0u;
          }
        }
      }
    }
}

// Block-cooperative barrier version, retained for S=2 layers (L4, L5).
template <int CIN, int COUT, int KK, int TI, int GIN, int GOUT, int S, int HB,
          int PADSTART, int PADEND>
__global__ __launch_bounds__(256) void conv_mfma(
    const ushort* __restrict__ xin, const ushort* __restrict__ Bg,
    const float* __restrict__ bias, ushort* __restrict__ out) {
  constexpr int WO = TI - KK + 1;
  constexpr int HTILES = WO / HB;
  constexpr int NC = CIN * KK * KK;
  constexpr int RS = 4 + HB - 1;
  constexpr int GW = (S == 4 ? 2 : 3);
  constexpr int ROWU = GW * 1024;
  constexpr int PROW = GW * 2;
  constexpr int sH = GIN * 1024, sD = TI * sH, sT = TI * sD, sC = TI * sT;
  constexpr int oH = GOUT * 1024, oD = WO * oH, oT = WO * oD, oC = WO * oT;

  __shared__ ushort slab[2][RS * ROWU];

  const int ht = blockIdx.x % HTILES;
  const int wt = blockIdx.x / HTILES;
  const int d = blockIdx.y, t = blockIdx.z;
  const int h0 = ht * HB, wb = wt * S;
  const int g0 = wb >> 2;

  const int tid = threadIdx.x;
  const int wave = tid >> 6, lane = tid & 63;
  const int quad = lane >> 4, mm = lane & 15;

  f32x4 acc[HB][4];
#pragma unroll
  for (int dh = 0; dh < HB; dh++)
#pragma unroll
    for (int bt = 0; bt < 4; bt++) acc[dh][bt] = (f32x4){0.f, 0.f, 0.f, 0.f};

  auto stage = [&](int c, int buf) {
    const int kd = c % KK, kt2 = (c / KK) % KK, ci = c / (KK * KK);
    const ushort* base =
        xin + ci * sC + (t + kt2) * sT + (d + kd) * sD + g0 * 1024;
    for (int r = wave; r < RS; r += 4) {
      int row = h0 + r;
      if (row > TI - 1) row = TI - 1;  // KK=3 tail rows (zero-weight) clamp
      const ushort* g = base + row * sH;
      ushort* l = &slab[buf][r * ROWU];
#pragma unroll
      for (int p = 0; p < PROW; p++) {
        __builtin_amdgcn_global_load_lds(
            (const GLOBAL_AS uint*)(const void*)(g + p * 512 + lane * 8),
            (LDS_AS uint*)(void*)(l + p * 512), 16, 0, 0);
      }
    }
  };

  stage(0, 0);

  for (int c = 0; c < NC; c++) {
    __syncthreads();
    if (c + 1 < NC) stage(c + 1, (c + 1) & 1);

    u32x4 traw = *(const u32x4*)(const void*)(Bg + c * 512 + mm * 32 + quad * 8);
    half8 tf = __builtin_bit_cast(half8, traw);
    const int buf = c & 1;

#pragma unroll
    for (int dh = 0; dh < HB; dh++) {
      const ushort* arow = &slab[buf][(dh + quad) * ROWU];
#pragma unroll
      for (int bt = 0; bt < 4; bt++) {
        const int bidx = ((wave * 4 + bt) * 16 + mm) * 4;
        u32x4 raw;
        if ((wb & 2) == 0) {
          uint2 lo = *(const uint2*)(const void*)(arow + bidx);
          uint2 hi = *(const uint2*)(const void*)(arow + 1024 + bidx);
          raw = (u32x4){lo.x, lo.y, hi.x, hi.y};
        } else {
          uint c0 = *(const uint*)(const void*)(arow + bidx + 2);
          uint2 md = *(const uint2*)(const void*)(arow + 1024 + bidx);
          uint c1 = *(const uint*)(const void*)(arow + 2048 + bidx);
          raw = (u32x4){c0, md.x, md.y, c1};
        }
        half8 xf = __builtin_bit_cast(half8, raw);
        acc[dh][bt] =
            __builtin_amdgcn_mfma_f32_16x16x32_f16(tf, xf, acc[dh][bt], 0, 0, 0);
      }
    }
  }

  const bool is_last = (wb + S >= WO);
#pragma unroll
  for (int dh = 0; dh < HB; dh++)
#pragma unroll
    for (int bt = 0; bt < 4; bt++) {
      const int b = (wave * 4 + bt) * 16 + mm;
      ushort* obase = out + t * oT + d * oD + (h0 + dh) * oH + b * 4;
      f32x4 v = acc[dh][bt];
      const int co0 = quad * 2, co1 = co0 + 1;
      if (co0 < COUT) {
        const float bv = bias[co0];
        float r0 = fmaxf(v[0] + bv, 0.f), r1 = fmaxf(v[1] + bv, 0.f);
        *(uint*)(void*)(obase + co0 * oC + g0 * 1024 + (wb & 3)) =
            (uint)f2h(r0) | ((uint)f2h(r1) << 16);
      }
      if (co1 < COUT) {
        const float bv = bias[co1];
        float r2 = fmaxf(v[2] + bv, 0.f), r3 = fmaxf(v[3] + bv, 0.f);
        *(uint*)(void*)(obase + co1 * oC + g0 * 1024 + (wb & 3)) =
            (uint)f2h(r2) | ((uint)f2h(r3) << 16);
      }
      if constexpr (PADEND > PADSTART) {
        if (is_last) {
#pragma unroll
          for (int cc = 0; cc < 2; cc++) {
            const int co = quad * 2 + cc;
            if (co < COUT) {
#pragma unroll
              for (int w = PADSTART; w < PADEND; w += 2)
                *(uint*)(void*)(obase + co * oC + (w >> 2) * 1024 + (w & 3)) =
                    0u;
            }
          }
        }
      }
    }
}

// h5 f16 [co][t][d][h][b][4] (= group layout, GOUT=1): u64-coalesced.
__global__ __launch_bounds__(256) void fc1_kernel(
    const ushort* __restrict__ h, const float* __restrict__ w,
    const float* __restrict__ bias, float* __restrict__ out) {
  const int o = blockIdx.x, b = threadIdx.x;
  const float* wr = w + o * 1280;
  float a0 = 0.f, a1 = 0.f, a2 = 0.f, a3 = 0.f;
#pragma unroll 4
  for (int kq = 0; kq < 320; kq++) {
    const uint2 hv = *(const uint2*)(const void*)(h + (kq * 256 + b) * 4);
    a0 = fmaf(h2f((ushort)(hv.x & 0xffffu)), wr[4 * kq + 0], a0);
    a1 = fmaf(h2f((ushort)(hv.x >> 16)), wr[4 * kq + 1], a1);
    a2 = fmaf(h2f((ushort)(hv.y & 0xffffu)), wr[4 * kq + 2], a2);
    a3 = fmaf(h2f((ushort)(hv.y >> 16)), wr[4 * kq + 3], a3);
  }
  float acc = (a0 + a1) + (a2 + a3) + bias[o];
  out[o * BATCH + b] = acc > 0.f ? acc : 0.f;
}

__global__ __launch_bounds__(256) void fc2_kernel(
    const float* __restrict__ r, const float* __restrict__ w,
    const float* __restrict__ bias, float* __restrict__ out) {
  const int b = threadIdx.x;
  float acc = bias[0];
#pragma unroll
  for (int o = 0; o < 33; o++) acc = fmaf(r[o * BATCH + b], w[o], acc);
  out[b] = 1.f / (1.f + expf(-acc));
}

extern "C" void kernel_launch(void* const* d_in, const int* in_sizes, int n_in,
                              void* d_out, int out_size, void* d_ws,
                              size_t ws_size, hipStream_t stream) {
  const float* x    = (const float*)d_in[0];
  const float* w1   = (const float*)d_in[1];
  const float* b1   = (const float*)d_in[2];
  const float* w2   = (const float*)d_in[3];
  const float* b2   = (const float*)d_in[4];
  const float* w3   = (const float*)d_in[5];
  const float* b3   = (const float*)d_in[6];
  const float* w4   = (const float*)d_in[7];
  const float* b4   = (const float*)d_in[8];
  const float* w5   = (const float*)d_in[9];
  const float* b5   = (const float*)d_in[10];
  const float* fc1w = (const float*)d_in[11];
  const float* fc1b = (const float*)d_in[12];
  const float* fc2w = (const float*)d_in[13];
  const float* fc2b = (const float*)d_in[14];
  float* out = (float*)d_out;

  // Workspace (u16 units), group layout [c][t][d][h][g][b][4]:
  // R0: xt 29,859,840 (G=5) / h2 21,233,664 (G=4) / h4 3,317,760 (G=3)
  // R1: h1 41,472,000 (G=4) / h3  8,957,952 (G=3) / h5   327,680 (G=1)
  ushort* wsu = (ushort*)d_ws;
  ushort* R0 = wsu;
  ushort* R1 = wsu + 29900000;
  ushort* Bgb = wsu + 71400000;      // 221*512 = 113,152 u16
  float* fo = (float*)(wsu + 71520000);

  ushort* xt = R0;
  ushort* h1 = R1;
  ushort* h2 = R0;
  ushort* h3 = R1;
  ushort* h4 = R0;
  ushort* h5 = R1;

  ushort* B1 = Bgb;                 // 16 chunks
  ushort* B2 = Bgb + 16 * 512;      // 48
  ushort* B3 = Bgb + 64 * 512;      // 48
  ushort* B4 = Bgb + 112 * 512;     // 64
  ushort* B5 = Bgb + 176 * 512;     // 45

  build_b<1, 3, 4, 4><<<16, 256, 0, stream>>>(w1, B1);
  build_b<3, 3, 4, 4><<<48, 256, 0, stream>>>(w2, B2);
  build_b<3, 4, 4, 4><<<48, 256, 0, stream>>>(w3, B3);
  build_b<4, 5, 4, 2><<<64, 256, 0, stream>>>(w4, B4);
  build_b<5, 5, 3, 2><<<45, 256, 0, stream>>>(w5, B5);

  transpose_kernel<<<dim3(821, 4), 256, 0, stream>>>(x, (uint*)xt);

  // Barrier-free per-wave convs (S=4), 1D grid + XCD swizzle:
  // <CIN,COUT,KK,TI,GIN,GOUT,HB,PADS,PADE>  NWG = HT*WT*WO^2
  conv_wave<1, 3, 4, 18, 5, 4, 5, 0, 0>     // CH=9,  slab 64KB, 2 blk/CU
      <<<2700, 256, 0, stream>>>(xt, B1, b1, h1);
  conv_wave<3, 3, 4, 15, 4, 4, 6, 12, 16>   // CH=10, slab 72KB, 2 blk/CU
      <<<864, 256, 0, stream>>>(h1, B2, b2, h2);
  conv_wave<3, 4, 4, 12, 4, 3, 3, 0, 0>     // CH=7,  slab 48KB, 3 blk/CU
      <<<729, 256, 0, stream>>>(h2, B3, b3, h3);

  // Small S=2 layers on the proven barrier template:
  conv_mfma<4, 5, 4, 9, 3, 3, 2, 2, 6, 12>
      <<<dim3(9, 6, 6), 256, 0, stream>>>(h3, B4, b4, h4);
  conv_mfma<5, 5, 3, 6, 3, 1, 2, 2, 0, 0>
      <<<dim3(4, 4, 4), 256, 0, stream>>>(h4, B5, b5, h5);

  fc1_kernel<<<33, 256, 0, stream>>>(h5, fc1w, fc1b, fo);
  fc2_kernel<<<1, 256, 0, stream>>>(fo, fc2w, fc2b, out);
}

// Round 14
// 643.108 us; speedup vs baseline: 1.5452x; 1.0217x over previous
//
#include <hip/hip_runtime.h>
#include <math.h>

#define BATCH 256
typedef unsigned int uint;
typedef unsigned short ushort;
typedef _Float16 half8 __attribute__((ext_vector_type(8)));
typedef float f32x4 __attribute__((ext_vector_type(4)));
typedef uint u32x4 __attribute__((ext_vector_type(4)));

#define GLOBAL_AS __attribute__((address_space(1)))
#define LDS_AS __attribute__((address_space(3)))

__device__ __forceinline__ ushort f2h(float f) {
  _Float16 h = (_Float16)f;
  return __builtin_bit_cast(ushort, h);
}
__device__ __forceinline__ float h2f(ushort u) {
  return (float)__builtin_bit_cast(_Float16, u);
}

// Counted vmcnt wait (T4). "memory" clobber orders memory ops across it;
// sched_barrier(0) pins instruction motion (rule-18 guard).
template <int N>
__device__ __forceinline__ void waitv() {
  if constexpr (N == 0) {
    asm volatile("s_waitcnt vmcnt(0)" ::: "memory");
  } else if constexpr (N == 7) {
    asm volatile("s_waitcnt vmcnt(7)" ::: "memory");
  } else if constexpr (N == 9) {
    asm volatile("s_waitcnt vmcnt(9)" ::: "memory");
  } else if constexpr (N == 10) {
    asm volatile("s_waitcnt vmcnt(10)" ::: "memory");
  } else {
    static_assert(N == 0 || N == 7 || N == 9 || N == 10, "add literal");
  }
  __builtin_amdgcn_sched_barrier(0);
}

// Bijective chunked XCD swizzle (T1, m204): consecutive logical blocks land
// on the same XCD so same-(t,d) blocks share one L2's input slabs.
template <int NWG>
__device__ __forceinline__ int xcd_swz(int bid) {
  constexpr int Q = NWG / 8, R = NWG % 8;
  const int x = bid & 7, i = bid >> 3;
  return (x < R ? x * (Q + 1) : R * (Q + 1) + (x - R) * Q) + i;
}

// x fp32 [256][P=18^4] -> xt group layout [sh=(t,d,h)][g=5][b=256][4w] u16.
// 64x64 u32-tile LDS transpose: coalesced 512B global reads AND uint2 writes.
__global__ __launch_bounds__(256) void transpose_kernel(
    const float* __restrict__ x, uint* __restrict__ xt) {
  __shared__ uint tile[65][65];
  const int P = 104976, NPP = 52488;
  const int pp0 = blockIdx.x * 64, b0 = blockIdx.y * 64;
  const int tx = threadIdx.x & 63, ty = threadIdx.x >> 6;
  for (int r = 0; r < 64; r += 4) {
    const int bl = ty + r, pp = pp0 + tx;
    if (pp < NPP) {
      const float2 v = *(const float2*)(x + (size_t)(b0 + bl) * P + 2 * pp);
      tile[tx][bl] = (uint)f2h(v.x) | ((uint)f2h(v.y) << 16);
    }
  }
  if (threadIdx.x < 64 && pp0 + 64 < NPP) {
    const int bl = threadIdx.x;
    const float2 v =
        *(const float2*)(x + (size_t)(b0 + bl) * P + 2 * (pp0 + 64));
    tile[64][bl] = (uint)f2h(v.x) | ((uint)f2h(v.y) << 16);
  }
  __syncthreads();
  for (int r = ty; r < 64; r += 4) {
    const int pp = pp0 + r;
    if (pp >= NPP) break;
    const int wp = pp % 9, sh = pp / 9;
    if (wp & 1) continue;
    uint2 o;
    o.x = tile[r][tx];
    o.y = (wp == 8) ? 0u : tile[r + 1][tx];
    *(uint2*)(xt + (size_t)(sh * 5 + (wp >> 1)) * 512 + (b0 + tx) * 2) = o;
  }
}

// Block-Toeplitz table: Bg[chunk][n=16][k=32] f16, chunk=(ci*KK+kt)*KK+kd,
// k=kh*8+wi, n=co*S+dw. B[k][n] = w[co][ci][kt][kd][kh][wi-dw] if valid else 0.
template <int CIN, int COUT, int KK, int S>
__global__ __launch_bounds__(256) void build_b(
    const float* __restrict__ w, ushort* __restrict__ Bg) {
  const int chunk = blockIdx.x;
  const int kd = chunk % KK, kt = (chunk / KK) % KK, ci = chunk / (KK * KK);
  for (int e = threadIdx.x; e < 512; e += 256) {
    int n = e >> 5, k = e & 31;
    int kh = k >> 3, wi = k & 7;
    int co = n / S, dw = n % S;
    int kw = wi - dw;
    float v = 0.f;
    if (co < COUT && kh < KK && kw >= 0 && kw < KK)
      v = w[((((co * CIN + ci) * KK + kt) * KK + kd) * KK + kh) * KK + kw];
    Bg[chunk * 512 + n * 32 + k] = f2h(v);
  }
}

// Barrier-free per-wave MFMA conv (S=4 layers). Per-wave private LDS slab,
// global_load_lds x-staging, tf loaded DIRECT global->VGPR (dwordx4, Bg is
// L2-resident), depth-2 pipeline with counted vmcnt. Per-chunk VMEM ops =
// RS x-rows + 1 tf = CH, so waitv<CH> completes chunk c with c+1 in flight.
// NO __syncthreads anywhere. 1D grid with XCD swizzle.
// HB=3 everywhere: RS=6 -> slab 48KB -> 3 blocks/CU (12 waves, latency
// hiding); staging +25-33% vs bigger HB but that stream is L2-absorbed.
template <int CIN, int COUT, int KK, int TI, int GIN, int GOUT, int HB,
          int PADSTART, int PADEND>
__global__ __launch_bounds__(256) void conv_wave(
    const ushort* __restrict__ xin, const ushort* __restrict__ Bg,
    const float* __restrict__ bias, ushort* __restrict__ out) {
  constexpr int S = 4;
  constexpr int WO = TI - KK + 1;
  constexpr int HTILES = WO / HB;
  constexpr int WTILES = (WO + S - 1) / S;
  constexpr int GX = HTILES * WTILES;
  constexpr int NWG = GX * WO * WO;
  constexpr int NC = CIN * KK * KK;
  static_assert(NC % 2 == 0, "pair-unrolled chunk loop needs even NC");
  constexpr int RS = 4 + HB - 1;   // staged h-rows (KHP=4); KK=4 -> no clamp
  constexpr int CH = RS + 1;       // VMEM ops per chunk (RS x-rows + 1 tf)
  constexpr int sH = GIN * 1024, sD = TI * sH, sT = TI * sD, sC = TI * sT;
  constexpr int oH = GOUT * 1024, oD = WO * oH, oT = WO * oD, oC = WO * oT;

  __shared__ ushort slab[4][2][RS * 512];  // [wave][buf]; 1KB per h-row

  const int wg = xcd_swz<NWG>(blockIdx.x);
  const int xb = wg % GX;
  const int d = (wg / GX) % WO;
  const int t = wg / (GX * WO);
  const int ht = xb % HTILES, wt = xb / HTILES;
  const int h0 = ht * HB, wb = wt * S;
  const int g0 = wb >> 2;

  const int tid = threadIdx.x;
  const int wave = tid >> 6, lane = tid & 63;
  const int quad = lane >> 4, mm = lane & 15;

  // x row src: lane covers (g = lane>>5, batches wave*64 + (lane&31)*2 ..+1)
  const int xsrc = (lane >> 5) * 1024 + wave * 256 + (lane & 31) * 8;
  const int bsrc = mm * 32 + quad * 8;  // per-lane 16B tf fragment in Bg

  f32x4 acc[HB][4];
#pragma unroll
  for (int dh = 0; dh < HB; dh++)
#pragma unroll
    for (int bt = 0; bt < 4; bt++) acc[dh][bt] = (f32x4){0.f, 0.f, 0.f, 0.f};

  auto stage = [&](int c, int buf) {
    const int kd = c % KK, kt2 = (c / KK) % KK, ci = c / (KK * KK);
    const ushort* base =
        xin + ci * sC + (t + kt2) * sT + (d + kd) * sD + h0 * sH + g0 * 1024;
    ushort* l = &slab[wave][buf][0];
#pragma unroll
    for (int r = 0; r < RS; r++)
      __builtin_amdgcn_global_load_lds(
          (const GLOBAL_AS uint*)(const void*)(base + r * sH + xsrc),
          (LDS_AS uint*)(void*)(l + r * 512), 16, 0, 0);
  };

  auto load_tf = [&](int c) -> u32x4 {
    return *(const u32x4*)(const void*)(Bg + c * 512 + bsrc);
  };

  auto compute = [&](int buf, u32x4 traw) {
    half8 tf = __builtin_bit_cast(half8, traw);
    const ushort* wsl = &slab[wave][buf][0];
#pragma unroll
    for (int dh = 0; dh < HB; dh++) {
      const ushort* arow = wsl + (dh + quad) * 512;
#pragma unroll
      for (int bt = 0; bt < 4; bt++) {
        const int bb = bt * 16 + mm;
        uint2 lo = *(const uint2*)(const void*)(arow + bb * 4);
        uint2 hi = *(const uint2*)(const void*)(arow + 256 + bb * 4);
        half8 xf = __builtin_bit_cast(half8, (u32x4){lo.x, lo.y, hi.x, hi.y});
        acc[dh][bt] =
            __builtin_amdgcn_mfma_f32_16x16x32_f16(tf, xf, acc[dh][bt], 0, 0, 0);
      }
    }
  };

  stage(0, 0);
  u32x4 tfA = load_tf(0);
  u32x4 tfB;

  for (int c = 0; c < NC; c += 2) {
    // prefetch odd chunk c+1 (always exists: NC even)
    tfB = load_tf(c + 1);
    stage(c + 1, 1);
    waitv<CH>();          // chunk c (x rows + tfA) landed; c+1 in flight
    compute(0, tfA);
    __builtin_amdgcn_sched_barrier(0);  // pin buf0 ds_reads before next stage
    if (c + 2 < NC) {
      tfA = load_tf(c + 2);
      stage(c + 2, 0);
      waitv<CH>();        // chunk c+1 landed; c+2 in flight
    } else {
      waitv<0>();
    }
    compute(1, tfB);
    __builtin_amdgcn_sched_barrier(0);  // pin buf1 ds_reads before next stage
  }

  // Epilogue: C/D row m=quad*4+reg = n (co*S+dw); col = mm.
  const bool is_last = (wb + S >= WO);
  const int co = quad;
#pragma unroll
  for (int dh = 0; dh < HB; dh++)
#pragma unroll
    for (int bt = 0; bt < 4; bt++) {
      const int b = wave * 64 + bt * 16 + mm;
      ushort* obase = out + t * oT + d * oD + (h0 + dh) * oH + b * 4;
      f32x4 v = acc[dh][bt];
      if (co < COUT) {
        const float bv = bias[co];
        float r0 = (wb + 0 < WO) ? fmaxf(v[0] + bv, 0.f) : 0.f;
        float r1 = (wb + 1 < WO) ? fmaxf(v[1] + bv, 0.f) : 0.f;
        float r2 = (wb + 2 < WO) ? fmaxf(v[2] + bv, 0.f) : 0.f;
        float r3 = (wb + 3 < WO) ? fmaxf(v[3] + bv, 0.f) : 0.f;
        uint2 pk;
        pk.x = (uint)f2h(r0) | ((uint)f2h(r1) << 16);
        pk.y = (uint)f2h(r2) | ((uint)f2h(r3) << 16);
        *(uint2*)(void*)(obase + co * oC + g0 * 1024) = pk;
        if constexpr (PADEND > PADSTART) {
          if (is_last) {
#pragma unroll
            for (int w = PADSTART; w < PADEND; w += 2)
              *(uint*)(void*)(obase + co * oC + (w >> 2) * 1024 + (w & 3)) = 0u;
          }
        }
      }
    }
}

// Block-cooperative barrier version, retained for S=2 layers (L4, L5).
template <int CIN, int COUT, int KK, int TI, int GIN, int GOUT, int S, int HB,
          int PADSTART, int PADEND>
__global__ __launch_bounds__(256) void conv_mfma(
    const ushort* __restrict__ xin, const ushort* __restrict__ Bg,
    const float* __restrict__ bias, ushort* __restrict__ out) {
  constexpr int WO = TI - KK + 1;
  constexpr int HTILES = WO / HB;
  constexpr int NC = CIN * KK * KK;
  constexpr int RS = 4 + HB - 1;
  constexpr int GW = (S == 4 ? 2 : 3);
  constexpr int ROWU = GW * 1024;
  constexpr int PROW = GW * 2;
  constexpr int sH = GIN * 1024, sD = TI * sH, sT = TI * sD, sC = TI * sT;
  constexpr int oH = GOUT * 1024, oD = WO * oH, oT = WO * oD, oC = WO * oT;

  __shared__ ushort slab[2][RS * ROWU];

  const int ht = blockIdx.x % HTILES;
  const int wt = blockIdx.x / HTILES;
  const int d = blockIdx.y, t = blockIdx.z;
  const int h0 = ht * HB, wb = wt * S;
  const int g0 = wb >> 2;

  const int tid = threadIdx.x;
  const int wave = tid >> 6, lane = tid & 63;
  const int quad = lane >> 4, mm = lane & 15;

  f32x4 acc[HB][4];
#pragma unroll
  for (int dh = 0; dh < HB; dh++)
#pragma unroll
    for (int bt = 0; bt < 4; bt++) acc[dh][bt] = (f32x4){0.f, 0.f, 0.f, 0.f};

  auto stage = [&](int c, int buf) {
    const int kd = c % KK, kt2 = (c / KK) % KK, ci = c / (KK * KK);
    const ushort* base =
        xin + ci * sC + (t + kt2) * sT + (d + kd) * sD + g0 * 1024;
    for (int r = wave; r < RS; r += 4) {
      int row = h0 + r;
      if (row > TI - 1) row = TI - 1;  // KK=3 tail rows (zero-weight) clamp
      const ushort* g = base + row * sH;
      ushort* l = &slab[buf][r * ROWU];
#pragma unroll
      for (int p = 0; p < PROW; p++) {
        __builtin_amdgcn_global_load_lds(
            (const GLOBAL_AS uint*)(const void*)(g + p * 512 + lane * 8),
            (LDS_AS uint*)(void*)(l + p * 512), 16, 0, 0);
      }
    }
  };

  stage(0, 0);

  for (int c = 0; c < NC; c++) {
    __syncthreads();
    if (c + 1 < NC) stage(c + 1, (c + 1) & 1);

    u32x4 traw = *(const u32x4*)(const void*)(Bg + c * 512 + mm * 32 + quad * 8);
    half8 tf = __builtin_bit_cast(half8, traw);
    const int buf = c & 1;

#pragma unroll
    for (int dh = 0; dh < HB; dh++) {
      const ushort* arow = &slab[buf][(dh + quad) * ROWU];
#pragma unroll
      for (int bt = 0; bt < 4; bt++) {
        const int bidx = ((wave * 4 + bt) * 16 + mm) * 4;
        u32x4 raw;
        if ((wb & 2) == 0) {
          uint2 lo = *(const uint2*)(const void*)(arow + bidx);
          uint2 hi = *(const uint2*)(const void*)(arow + 1024 + bidx);
          raw = (u32x4){lo.x, lo.y, hi.x, hi.y};
        } else {
          uint c0 = *(const uint*)(const void*)(arow + bidx + 2);
          uint2 md = *(const uint2*)(const void*)(arow + 1024 + bidx);
          uint c1 = *(const uint*)(const void*)(arow + 2048 + bidx);
          raw = (u32x4){c0, md.x, md.y, c1};
        }
        half8 xf = __builtin_bit_cast(half8, raw);
        acc[dh][bt] =
            __builtin_amdgcn_mfma_f32_16x16x32_f16(tf, xf, acc[dh][bt], 0, 0, 0);
      }
    }
  }

  const bool is_last = (wb + S >= WO);
#pragma unroll
  for (int dh = 0; dh < HB; dh++)
#pragma unroll
    for (int bt = 0; bt < 4; bt++) {
      const int b = (wave * 4 + bt) * 16 + mm;
      ushort* obase = out + t * oT + d * oD + (h0 + dh) * oH + b * 4;
      f32x4 v = acc[dh][bt];
      const int co0 = quad * 2, co1 = co0 + 1;
      if (co0 < COUT) {
        const float bv = bias[co0];
        float r0 = fmaxf(v[0] + bv, 0.f), r1 = fmaxf(v[1] + bv, 0.f);
        *(uint*)(void*)(obase + co0 * oC + g0 * 1024 + (wb & 3)) =
            (uint)f2h(r0) | ((uint)f2h(r1) << 16);
      }
      if (co1 < COUT) {
        const float bv = bias[co1];
        float r2 = fmaxf(v[2] + bv, 0.f), r3 = fmaxf(v[3] + bv, 0.f);
        *(uint*)(void*)(obase + co1 * oC + g0 * 1024 + (wb & 3)) =
            (uint)f2h(r2) | ((uint)f2h(r3) << 16);
      }
      if constexpr (PADEND > PADSTART) {
        if (is_last) {
#pragma unroll
          for (int cc = 0; cc < 2; cc++) {
            const int co = quad * 2 + cc;
            if (co < COUT) {
#pragma unroll
              for (int w = PADSTART; w < PADEND; w += 2)
                *(uint*)(void*)(obase + co * oC + (w >> 2) * 1024 + (w & 3)) =
                    0u;
            }
          }
        }
      }
    }
}

// h5 f16 [co][t][d][h][b][4] (= group layout, GOUT=1): u64-coalesced.
__global__ __launch_bounds__(256) void fc1_kernel(
    const ushort* __restrict__ h, const float* __restrict__ w,
    const float* __restrict__ bias, float* __restrict__ out) {
  const int o = blockIdx.x, b = threadIdx.x;
  const float* wr = w + o * 1280;
  float a0 = 0.f, a1 = 0.f, a2 = 0.f, a3 = 0.f;
#pragma unroll 4
  for (int kq = 0; kq < 320; kq++) {
    const uint2 hv = *(const uint2*)(const void*)(h + (kq * 256 + b) * 4);
    a0 = fmaf(h2f((ushort)(hv.x & 0xffffu)), wr[4 * kq + 0], a0);
    a1 = fmaf(h2f((ushort)(hv.x >> 16)), wr[4 * kq + 1], a1);
    a2 = fmaf(h2f((ushort)(hv.y & 0xffffu)), wr[4 * kq + 2], a2);
    a3 = fmaf(h2f((ushort)(hv.y >> 16)), wr[4 * kq + 3], a3);
  }
  float acc = (a0 + a1) + (a2 + a3) + bias[o];
  out[o * BATCH + b] = acc > 0.f ? acc : 0.f;
}

__global__ __launch_bounds__(256) void fc2_kernel(
    const float* __restrict__ r, const float* __restrict__ w,
    const float* __restrict__ bias, float* __restrict__ out) {
  const int b = threadIdx.x;
  float acc = bias[0];
#pragma unroll
  for (int o = 0; o < 33; o++) acc = fmaf(r[o * BATCH + b], w[o], acc);
  out[b] = 1.f / (1.f + expf(-acc));
}

extern "C" void kernel_launch(void* const* d_in, const int* in_sizes, int n_in,
                              void* d_out, int out_size, void* d_ws,
                              size_t ws_size, hipStream_t stream) {
  const float* x    = (const float*)d_in[0];
  const float* w1   = (const float*)d_in[1];
  const float* b1   = (const float*)d_in[2];
  const float* w2   = (const float*)d_in[3];
  const float* b2   = (const float*)d_in[4];
  const float* w3   = (const float*)d_in[5];
  const float* b3   = (const float*)d_in[6];
  const float* w4   = (const float*)d_in[7];
  const float* b4   = (const float*)d_in[8];
  const float* w5   = (const float*)d_in[9];
  const float* b5   = (const float*)d_in[10];
  const float* fc1w = (const float*)d_in[11];
  const float* fc1b = (const float*)d_in[12];
  const float* fc2w = (const float*)d_in[13];
  const float* fc2b = (const float*)d_in[14];
  float* out = (float*)d_out;

  // Workspace (u16 units), group layout [c][t][d][h][g][b][4]:
  // R0: xt 29,859,840 (G=5) / h2 21,233,664 (G=4) / h4 3,317,760 (G=3)
  // R1: h1 41,472,000 (G=4) / h3  8,957,952 (G=3) / h5   327,680 (G=1)
  ushort* wsu = (ushort*)d_ws;
  ushort* R0 = wsu;
  ushort* R1 = wsu + 29900000;
  ushort* Bgb = wsu + 71400000;      // 221*512 = 113,152 u16
  float* fo = (float*)(wsu + 71520000);

  ushort* xt = R0;
  ushort* h1 = R1;
  ushort* h2 = R0;
  ushort* h3 = R1;
  ushort* h4 = R0;
  ushort* h5 = R1;

  ushort* B1 = Bgb;                 // 16 chunks
  ushort* B2 = Bgb + 16 * 512;      // 48
  ushort* B3 = Bgb + 64 * 512;      // 48
  ushort* B4 = Bgb + 112 * 512;     // 64
  ushort* B5 = Bgb + 176 * 512;     // 45

  build_b<1, 3, 4, 4><<<16, 256, 0, stream>>>(w1, B1);
  build_b<3, 3, 4, 4><<<48, 256, 0, stream>>>(w2, B2);
  build_b<3, 4, 4, 4><<<48, 256, 0, stream>>>(w3, B3);
  build_b<4, 5, 4, 2><<<64, 256, 0, stream>>>(w4, B4);
  build_b<5, 5, 3, 2><<<45, 256, 0, stream>>>(w5, B5);

  transpose_kernel<<<dim3(821, 4), 256, 0, stream>>>(x, (uint*)xt);

  // Barrier-free per-wave convs (S=4), 1D grid + XCD swizzle, HB=3 ->
  // slab 48KB -> 3 blocks/CU (12 waves) on all three layers:
  // <CIN,COUT,KK,TI,GIN,GOUT,HB,PADS,PADE>  NWG = HT*WT*WO^2
  conv_wave<1, 3, 4, 18, 5, 4, 3, 0, 0>     // CH=7, NWG=4500
      <<<4500, 256, 0, stream>>>(xt, B1, b1, h1);
  conv_wave<3, 3, 4, 15, 4, 4, 3, 12, 16>   // CH=7, NWG=1728
      <<<1728, 256, 0, stream>>>(h1, B2, b2, h2);
  conv_wave<3, 4, 4, 12, 4, 3, 3, 0, 0>     // CH=7, NWG=729
      <<<729, 256, 0, stream>>>(h2, B3, b3, h3);

  // Small S=2 layers on the proven barrier template:
  conv_mfma<4, 5, 4, 9, 3, 3, 2, 2, 6, 12>
      <<<dim3(9, 6, 6), 256, 0, stream>>>(h3, B4, b4, h4);
  conv_mfma<5, 5, 3, 6, 3, 1, 2, 2, 0, 0>
      <<<dim3(4, 4, 4), 256, 0, stream>>>(h4, B5, b5, h5);

  fc1_kernel<<<33, 256, 0, stream>>>(h5, fc1w, fc1b, fo);
  fc2_kernel<<<1, 256, 0, stream>>>(fo, fc2w, fc2b, out);
}

// Round 18
// 580.272 us; speedup vs baseline: 1.7125x; 1.1083x over previous
//
#include <hip/hip_runtime.h>
#include <math.h>

#define BATCH 256
typedef unsigned int uint;
typedef unsigned short ushort;
typedef _Float16 half8 __attribute__((ext_vector_type(8)));
typedef float f32x4 __attribute__((ext_vector_type(4)));
typedef uint u32x4 __attribute__((ext_vector_type(4)));

#define GLOBAL_AS __attribute__((address_space(1)))
#define LDS_AS __attribute__((address_space(3)))

__device__ __forceinline__ ushort f2h(float f) {
  _Float16 h = (_Float16)f;
  return __builtin_bit_cast(ushort, h);
}
__device__ __forceinline__ float h2f(ushort u) {
  return (float)__builtin_bit_cast(_Float16, u);
}

// Counted vmcnt wait (T4). "memory" clobber orders memory ops across it;
// sched_barrier(0) pins instruction motion (rule-18 guard).
template <int N>
__device__ __forceinline__ void waitv() {
  if constexpr (N == 0) {
    asm volatile("s_waitcnt vmcnt(0)" ::: "memory");
  } else if constexpr (N == 7) {
    asm volatile("s_waitcnt vmcnt(7)" ::: "memory");
  } else if constexpr (N == 9) {
    asm volatile("s_waitcnt vmcnt(9)" ::: "memory");
  } else if constexpr (N == 10) {
    asm volatile("s_waitcnt vmcnt(10)" ::: "memory");
  } else {
    static_assert(N == 0 || N == 7 || N == 9 || N == 10, "add literal");
  }
  __builtin_amdgcn_sched_barrier(0);
}

// Bijective chunked XCD swizzle (T1, m204): consecutive logical blocks land
// on the same XCD so same-(t,d) blocks share one L2's input slabs.
template <int NWG>
__device__ __forceinline__ int xcd_swz(int bid) {
  constexpr int Q = NWG / 8, R = NWG % 8;
  const int x = bid & 7, i = bid >> 3;
  return (x < R ? x * (Q + 1) : R * (Q + 1) + (x - R) * Q) + i;
}

// x fp32 [256][P=18^4] -> xt group layout [sh=(t,d,h)][g=5][b=256][4w] u16.
// 64x64 u32-tile LDS transpose: coalesced 512B global reads AND uint2 writes.
__global__ __launch_bounds__(256) void transpose_kernel(
    const float* __restrict__ x, uint* __restrict__ xt) {
  __shared__ uint tile[65][65];
  const int P = 104976, NPP = 52488;
  const int pp0 = blockIdx.x * 64, b0 = blockIdx.y * 64;
  const int tx = threadIdx.x & 63, ty = threadIdx.x >> 6;
  for (int r = 0; r < 64; r += 4) {
    const int bl = ty + r, pp = pp0 + tx;
    if (pp < NPP) {
      const float2 v = *(const float2*)(x + (size_t)(b0 + bl) * P + 2 * pp);
      tile[tx][bl] = (uint)f2h(v.x) | ((uint)f2h(v.y) << 16);
    }
  }
  if (threadIdx.x < 64 && pp0 + 64 < NPP) {
    const int bl = threadIdx.x;
    const float2 v =
        *(const float2*)(x + (size_t)(b0 + bl) * P + 2 * (pp0 + 64));
    tile[64][bl] = (uint)f2h(v.x) | ((uint)f2h(v.y) << 16);
  }
  __syncthreads();
  for (int r = ty; r < 64; r += 4) {
    const int pp = pp0 + r;
    if (pp >= NPP) break;
    const int wp = pp % 9, sh = pp / 9;
    if (wp & 1) continue;
    uint2 o;
    o.x = tile[r][tx];
    o.y = (wp == 8) ? 0u : tile[r + 1][tx];
    *(uint2*)(xt + (size_t)(sh * 5 + (wp >> 1)) * 512 + (b0 + tx) * 2) = o;
  }
}

// Block-Toeplitz table: Bg[chunk][n=16][k=32] f16, chunk=(ci*KK+kt)*KK+kd,
// k=kh*8+wi, n=co*S+dw. B[k][n] = w[co][ci][kt][kd][kh][wi-dw] if valid else 0.
template <int CIN, int COUT, int KK, int S>
__global__ __launch_bounds__(256) void build_b(
    const float* __restrict__ w, ushort* __restrict__ Bg) {
  const int chunk = blockIdx.x;
  const int kd = chunk % KK, kt = (chunk / KK) % KK, ci = chunk / (KK * KK);
  for (int e = threadIdx.x; e < 512; e += 256) {
    int n = e >> 5, k = e & 31;
    int kh = k >> 3, wi = k & 7;
    int co = n / S, dw = n % S;
    int kw = wi - dw;
    float v = 0.f;
    if (co < COUT && kh < KK && kw >= 0 && kw < KK)
      v = w[((((co * CIN + ci) * KK + kt) * KK + kd) * KK + kh) * KK + kw];
    Bg[chunk * 512 + n * 32 + k] = f2h(v);
  }
}

// Barrier-free per-wave MFMA conv (S=4 layers). Per-wave private LDS slab,
// global_load_lds x-staging, tf loaded DIRECT global->VGPR (dwordx4, Bg is
// L2-resident), depth-2 pipeline with counted vmcnt. Per-chunk VMEM ops =
// RS x-rows + 1 tf = CH, so waitv<CH> completes chunk c with c+1 in flight.
// NO __syncthreads anywhere. 1D grid with XCD swizzle.
// HB=3: RS=6 -> slab 48KB -> 3 blocks/CU. NOTE (R14): these layers are
// LDS-BW-bound (~70 B/cyc/CU, near ds_read ceiling); dur tracks LDS bytes.
template <int CIN, int COUT, int KK, int TI, int GIN, int GOUT, int HB,
          int PADSTART, int PADEND>
__global__ __launch_bounds__(256) void conv_wave(
    const ushort* __restrict__ xin, const ushort* __restrict__ Bg,
    const float* __restrict__ bias, ushort* __restrict__ out) {
  constexpr int S = 4;
  constexpr int WO = TI - KK + 1;
  constexpr int HTILES = WO / HB;
  constexpr int WTILES = (WO + S - 1) / S;
  constexpr int GX = HTILES * WTILES;
  constexpr int NWG = GX * WO * WO;
  constexpr int NC = CIN * KK * KK;
  static_assert(NC % 2 == 0, "pair-unrolled chunk loop needs even NC");
  constexpr int RS = 4 + HB - 1;   // staged h-rows (KHP=4); KK=4 -> no clamp
  constexpr int CH = RS + 1;       // VMEM ops per chunk (RS x-rows + 1 tf)
  constexpr int sH = GIN * 1024, sD = TI * sH, sT = TI * sD, sC = TI * sT;
  constexpr int oH = GOUT * 1024, oD = WO * oH, oT = WO * oD, oC = WO * oT;

  __shared__ ushort slab[4][2][RS * 512];  // [wave][buf]; 1KB per h-row

  const int wg = xcd_swz<NWG>(blockIdx.x);
  const int xb = wg % GX;
  const int d = (wg / GX) % WO;
  const int t = wg / (GX * WO);
  const int ht = xb % HTILES, wt = xb / HTILES;
  const int h0 = ht * HB, wb = wt * S;
  const int g0 = wb >> 2;

  const int tid = threadIdx.x;
  const int wave = tid >> 6, lane = tid & 63;
  const int quad = lane >> 4, mm = lane & 15;

  // x row src: lane covers (g = lane>>5, batches wave*64 + (lane&31)*2 ..+1)
  const int xsrc = (lane >> 5) * 1024 + wave * 256 + (lane & 31) * 8;
  const int bsrc = mm * 32 + quad * 8;  // per-lane 16B tf fragment in Bg

  f32x4 acc[HB][4];
#pragma unroll
  for (int dh = 0; dh < HB; dh++)
#pragma unroll
    for (int bt = 0; bt < 4; bt++) acc[dh][bt] = (f32x4){0.f, 0.f, 0.f, 0.f};

  auto stage = [&](int c, int buf) {
    const int kd = c % KK, kt2 = (c / KK) % KK, ci = c / (KK * KK);
    const ushort* base =
        xin + ci * sC + (t + kt2) * sT + (d + kd) * sD + h0 * sH + g0 * 1024;
    ushort* l = &slab[wave][buf][0];
#pragma unroll
    for (int r = 0; r < RS; r++)
      __builtin_amdgcn_global_load_lds(
          (const GLOBAL_AS uint*)(const void*)(base + r * sH + xsrc),
          (LDS_AS uint*)(void*)(l + r * 512), 16, 0, 0);
  };

  auto load_tf = [&](int c) -> u32x4 {
    return *(const u32x4*)(const void*)(Bg + c * 512 + bsrc);
  };

  auto compute = [&](int buf, u32x4 traw) {
    half8 tf = __builtin_bit_cast(half8, traw);
    const ushort* wsl = &slab[wave][buf][0];
#pragma unroll
    for (int dh = 0; dh < HB; dh++) {
      const ushort* arow = wsl + (dh + quad) * 512;
#pragma unroll
      for (int bt = 0; bt < 4; bt++) {
        const int bb = bt * 16 + mm;
        uint2 lo = *(const uint2*)(const void*)(arow + bb * 4);
        uint2 hi = *(const uint2*)(const void*)(arow + 256 + bb * 4);
        half8 xf = __builtin_bit_cast(half8, (u32x4){lo.x, lo.y, hi.x, hi.y});
        acc[dh][bt] =
            __builtin_amdgcn_mfma_f32_16x16x32_f16(tf, xf, acc[dh][bt], 0, 0, 0);
      }
    }
  };

  stage(0, 0);
  u32x4 tfA = load_tf(0);
  u32x4 tfB;

  for (int c = 0; c < NC; c += 2) {
    // prefetch odd chunk c+1 (always exists: NC even)
    tfB = load_tf(c + 1);
    stage(c + 1, 1);
    waitv<CH>();          // chunk c (x rows + tfA) landed; c+1 in flight
    compute(0, tfA);
    __builtin_amdgcn_sched_barrier(0);  // pin buf0 ds_reads before next stage
    if (c + 2 < NC) {
      tfA = load_tf(c + 2);
      stage(c + 2, 0);
      waitv<CH>();        // chunk c+1 landed; c+2 in flight
    } else {
      waitv<0>();
    }
    compute(1, tfB);
    __builtin_amdgcn_sched_barrier(0);  // pin buf1 ds_reads before next stage
  }

  // Epilogue: C/D row m=quad*4+reg = n (co*S+dw); col = mm.
  const bool is_last = (wb + S >= WO);
  const int co = quad;
#pragma unroll
  for (int dh = 0; dh < HB; dh++)
#pragma unroll
    for (int bt = 0; bt < 4; bt++) {
      const int b = wave * 64 + bt * 16 + mm;
      ushort* obase = out + t * oT + d * oD + (h0 + dh) * oH + b * 4;
      f32x4 v = acc[dh][bt];
      if (co < COUT) {
        const float bv = bias[co];
        float r0 = (wb + 0 < WO) ? fmaxf(v[0] + bv, 0.f) : 0.f;
        float r1 = (wb + 1 < WO) ? fmaxf(v[1] + bv, 0.f) : 0.f;
        float r2 = (wb + 2 < WO) ? fmaxf(v[2] + bv, 0.f) : 0.f;
        float r3 = (wb + 3 < WO) ? fmaxf(v[3] + bv, 0.f) : 0.f;
        uint2 pk;
        pk.x = (uint)f2h(r0) | ((uint)f2h(r1) << 16);
        pk.y = (uint)f2h(r2) | ((uint)f2h(r3) << 16);
        *(uint2*)(void*)(obase + co * oC + g0 * 1024) = pk;
        if constexpr (PADEND > PADSTART) {
          if (is_last) {
#pragma unroll
            for (int w = PADSTART; w < PADEND; w += 2)
              *(uint*)(void*)(obase + co * oC + (w >> 2) * 1024 + (w & 3)) = 0u;
          }
        }
      }
    }
}

// Block-cooperative barrier version, retained for S=2 layers (L4, L5).
// HB=1 (R15): doubles grid for these grid-starved small layers.
template <int CIN, int COUT, int KK, int TI, int GIN, int GOUT, int S, int HB,
          int PADSTART, int PADEND>
__global__ __launch_bounds__(256) void conv_mfma(
    const ushort* __restrict__ xin, const ushort* __restrict__ Bg,
    const float* __restrict__ bias, ushort* __restrict__ out) {
  constexpr int WO = TI - KK + 1;
  constexpr int HTILES = WO / HB;
  constexpr int NC = CIN * KK * KK;
  constexpr int RS = 4 + HB - 1;
  constexpr int GW = (S == 4 ? 2 : 3);
  constexpr int ROWU = GW * 1024;
  constexpr int PROW = GW * 2;
  constexpr int sH = GIN * 1024, sD = TI * sH, sT = TI * sD, sC = TI * sT;
  constexpr int oH = GOUT * 1024, oD = WO * oH, oT = WO * oD, oC = WO * oT;

  __shared__ ushort slab[2][RS * ROWU];

  const int ht = blockIdx.x % HTILES;
  const int wt = blockIdx.x / HTILES;
  const int d = blockIdx.y, t = blockIdx.z;
  const int h0 = ht * HB, wb = wt * S;
  const int g0 = wb >> 2;

  const int tid = threadIdx.x;
  const int wave = tid >> 6, lane = tid & 63;
  const int quad = lane >> 4, mm = lane & 15;

  f32x4 acc[HB][4];
#pragma unroll
  for (int dh = 0; dh < HB; dh++)
#pragma unroll
    for (int bt = 0; bt < 4; bt++) acc[dh][bt] = (f32x4){0.f, 0.f, 0.f, 0.f};

  auto stage = [&](int c, int buf) {
    const int kd = c % KK, kt2 = (c / KK) % KK, ci = c / (KK * KK);
    const ushort* base =
        xin + ci * sC + (t + kt2) * sT + (d + kd) * sD + g0 * 1024;
    for (int r = wave; r < RS; r += 4) {
      int row = h0 + r;
      if (row > TI - 1) row = TI - 1;  // KK=3 tail rows (zero-weight) clamp
      const ushort* g = base + row * sH;
      ushort* l = &slab[buf][r * ROWU];
#pragma unroll
      for (int p = 0; p < PROW; p++) {
        __builtin_amdgcn_global_load_lds(
            (const GLOBAL_AS uint*)(const void*)(g + p * 512 + lane * 8),
            (LDS_AS uint*)(void*)(l + p * 512), 16, 0, 0);
      }
    }
  };

  stage(0, 0);

  for (int c = 0; c < NC; c++) {
    __syncthreads();
    if (c + 1 < NC) stage(c + 1, (c + 1) & 1);

    u32x4 traw = *(const u32x4*)(const void*)(Bg + c * 512 + mm * 32 + quad * 8);
    half8 tf = __builtin_bit_cast(half8, traw);
    const int buf = c & 1;

#pragma unroll
    for (int dh = 0; dh < HB; dh++) {
      const ushort* arow = &slab[buf][(dh + quad) * ROWU];
#pragma unroll
      for (int bt = 0; bt < 4; bt++) {
        const int bidx = ((wave * 4 + bt) * 16 + mm) * 4;
        u32x4 raw;
        if ((wb & 2) == 0) {
          uint2 lo = *(const uint2*)(const void*)(arow + bidx);
          uint2 hi = *(const uint2*)(const void*)(arow + 1024 + bidx);
          raw = (u32x4){lo.x, lo.y, hi.x, hi.y};
        } else {
          uint c0 = *(const uint*)(const void*)(arow + bidx + 2);
          uint2 md = *(const uint2*)(const void*)(arow + 1024 + bidx);
          uint c1 = *(const uint*)(const void*)(arow + 2048 + bidx);
          raw = (u32x4){c0, md.x, md.y, c1};
        }
        half8 xf = __builtin_bit_cast(half8, raw);
        acc[dh][bt] =
            __builtin_amdgcn_mfma_f32_16x16x32_f16(tf, xf, acc[dh][bt], 0, 0, 0);
      }
    }
  }

  const bool is_last = (wb + S >= WO);
#pragma unroll
  for (int dh = 0; dh < HB; dh++)
#pragma unroll
    for (int bt = 0; bt < 4; bt++) {
      const int b = (wave * 4 + bt) * 16 + mm;
      ushort* obase = out + t * oT + d * oD + (h0 + dh) * oH + b * 4;
      f32x4 v = acc[dh][bt];
      const int co0 = quad * 2, co1 = co0 + 1;
      if (co0 < COUT) {
        const float bv = bias[co0];
        float r0 = fmaxf(v[0] + bv, 0.f), r1 = fmaxf(v[1] + bv, 0.f);
        *(uint*)(void*)(obase + co0 * oC + g0 * 1024 + (wb & 3)) =
            (uint)f2h(r0) | ((uint)f2h(r1) << 16);
      }
      if (co1 < COUT) {
        const float bv = bias[co1];
        float r2 = fmaxf(v[2] + bv, 0.f), r3 = fmaxf(v[3] + bv, 0.f);
        *(uint*)(void*)(obase + co1 * oC + g0 * 1024 + (wb & 3)) =
            (uint)f2h(r2) | ((uint)f2h(r3) << 16);
      }
      if constexpr (PADEND > PADSTART) {
        if (is_last) {
#pragma unroll
          for (int cc = 0; cc < 2; cc++) {
            const int co = quad * 2 + cc;
            if (co < COUT) {
#pragma unroll
              for (int w = PADSTART; w < PADEND; w += 2)
                *(uint*)(void*)(obase + co * oC + (w >> 2) * 1024 + (w & 3)) =
                    0u;
            }
          }
        }
      }
    }
}

// fc1, k-sliced: grid (33, 8). Slice s covers kq [s*40, s*40+40).
// Writes PARTIAL sums (no bias/relu) to fo[(s*33+o)*256+b]; fc2 reduces.
__global__ __launch_bounds__(256) void fc1_kernel(
    const ushort* __restrict__ h, const float* __restrict__ w,
    float* __restrict__ out) {
  const int o = blockIdx.x, s = blockIdx.y, b = threadIdx.x;
  const float* wr = w + o * 1280 + s * 160;
  const ushort* hs = h + s * 40 * 1024;
  float a0 = 0.f, a1 = 0.f, a2 = 0.f, a3 = 0.f;
#pragma unroll 4
  for (int kq = 0; kq < 40; kq++) {
    const uint2 hv = *(const uint2*)(const void*)(hs + kq * 1024 + b * 4);
    a0 = fmaf(h2f((ushort)(hv.x & 0xffffu)), wr[4 * kq + 0], a0);
    a1 = fmaf(h2f((ushort)(hv.x >> 16)), wr[4 * kq + 1], a1);
    a2 = fmaf(h2f((ushort)(hv.y & 0xffffu)), wr[4 * kq + 2], a2);
    a3 = fmaf(h2f((ushort)(hv.y >> 16)), wr[4 * kq + 3], a3);
  }
  out[(s * 33 + o) * BATCH + b] = (a0 + a1) + (a2 + a3);
}

// fc2: reduce fc1 slices, +bias, ReLU, dot, sigmoid.
__global__ __launch_bounds__(256) void fc2_kernel(
    const float* __restrict__ r, const float* __restrict__ fc1b,
    const float* __restrict__ w, const float* __restrict__ fc2b,
    float* __restrict__ out) {
  const int b = threadIdx.x;
  float acc = fc2b[0];
#pragma unroll
  for (int o = 0; o < 33; o++) {
    float t = fc1b[o];
#pragma unroll
    for (int s = 0; s < 8; s++) t += r[(s * 33 + o) * BATCH + b];
    acc = fmaf(t > 0.f ? t : 0.f, w[o], acc);
  }
  out[b] = 1.f / (1.f + expf(-acc));
}

extern "C" void kernel_launch(void* const* d_in, const int* in_sizes, int n_in,
                              void* d_out, int out_size, void* d_ws,
                              size_t ws_size, hipStream_t stream) {
  const float* x    = (const float*)d_in[0];
  const float* w1   = (const float*)d_in[1];
  const float* b1   = (const float*)d_in[2];
  const float* w2   = (const float*)d_in[3];
  const float* b2   = (const float*)d_in[4];
  const float* w3   = (const float*)d_in[5];
  const float* b3   = (const float*)d_in[6];
  const float* w4   = (const float*)d_in[7];
  const float* b4   = (const float*)d_in[8];
  const float* w5   = (const float*)d_in[9];
  const float* b5   = (const float*)d_in[10];
  const float* fc1w = (const float*)d_in[11];
  const float* fc1b = (const float*)d_in[12];
  const float* fc2w = (const float*)d_in[13];
  const float* fc2b = (const float*)d_in[14];
  float* out = (float*)d_out;

  // Workspace (u16 units), group layout [c][t][d][h][g][b][4]:
  // R0: xt 29,859,840 (G=5) / h2 21,233,664 (G=4) / h4 3,317,760 (G=3)
  // R1: h1 41,472,000 (G=4) / h3  8,957,952 (G=3) / h5   327,680 (G=1)
  ushort* wsu = (ushort*)d_ws;
  ushort* R0 = wsu;
  ushort* R1 = wsu + 29900000;
  ushort* Bgb = wsu + 71400000;      // 221*512 = 113,152 u16
  float* fo = (float*)(wsu + 71520000);  // 8*33*256 f32 = 270 KB

  ushort* xt = R0;
  ushort* h1 = R1;
  ushort* h2 = R0;
  ushort* h3 = R1;
  ushort* h4 = R0;
  ushort* h5 = R1;

  ushort* B1 = Bgb;                 // 16 chunks
  ushort* B2 = Bgb + 16 * 512;      // 48
  ushort* B3 = Bgb + 64 * 512;      // 48
  ushort* B4 = Bgb + 112 * 512;     // 64
  ushort* B5 = Bgb + 176 * 512;     // 45

  build_b<1, 3, 4, 4><<<16, 256, 0, stream>>>(w1, B1);
  build_b<3, 3, 4, 4><<<48, 256, 0, stream>>>(w2, B2);
  build_b<3, 4, 4, 4><<<48, 256, 0, stream>>>(w3, B3);
  build_b<4, 5, 4, 2><<<64, 256, 0, stream>>>(w4, B4);
  build_b<5, 5, 3, 2><<<45, 256, 0, stream>>>(w5, B5);

  transpose_kernel<<<dim3(821, 4), 256, 0, stream>>>(x, (uint*)xt);

  // Barrier-free per-wave convs (S=4), 1D grid + XCD swizzle, HB=3 ->
  // slab 48KB -> 3 blocks/CU (12 waves); LDS-BW-bound (R14):
  // <CIN,COUT,KK,TI,GIN,GOUT,HB,PADS,PADE>  NWG = HT*WT*WO^2
  conv_wave<1, 3, 4, 18, 5, 4, 3, 0, 0>     // CH=7, NWG=4500
      <<<4500, 256, 0, stream>>>(xt, B1, b1, h1);
  conv_wave<3, 3, 4, 15, 4, 4, 3, 12, 16>   // CH=7, NWG=1728
      <<<1728, 256, 0, stream>>>(h1, B2, b2, h2);
  conv_wave<3, 4, 4, 12, 4, 3, 3, 0, 0>     // CH=7, NWG=729
      <<<729, 256, 0, stream>>>(h2, B3, b3, h3);

  // Small S=2 layers, HB=1 doubles grid (were grid-starved):
  conv_mfma<4, 5, 4, 9, 3, 3, 2, 1, 6, 12>
      <<<dim3(18, 6, 6), 256, 0, stream>>>(h3, B4, b4, h4);
  conv_mfma<5, 5, 3, 6, 3, 1, 2, 1, 0, 0>
      <<<dim3(8, 4, 4), 256, 0, stream>>>(h4, B5, b5, h5);

  fc1_kernel<<<dim3(33, 8), 256, 0, stream>>>(h5, fc1w, fo);
  fc2_kernel<<<1, 256, 0, stream>>>(fo, fc1b, fc2w, fc2b, out);
}